// Round 7
// baseline (1077.847 us; speedup 1.0000x reference)
//
#include <hip/hip_runtime.h>

// ---------------------------------------------------------------------------
// GCN 2-layer: out = A_norm * relu(A_norm*(X@W1)+b1) @ W2 + b2
// A_norm = D^-1/2 (A + I) D^-1/2.
//
// Round-7: bucket-accumulate aggregation. Edges bucket-grouped (256 dests per
// bucket) by a 1-pass scatter; aggregation kernels process one (bucket,slice)
// per block, accumulating 32 bf16 channels into an LDS fp32 accumulator via
// ds_add_f32. No per-node CSR, no second sort pass, slice-major layouts keep
// each 3.2 MB slice table L2-resident per XCD.
//   hs  = bf16( dinv * (X@W1) )   slice-major [4][n][32]    [gemm1, MFMA]
//   h1  = relu(dinv*(A.hs)+b1)    slice-major [4][n][32]    [agg1 x4 slices]
//   ps2 = bf16( dinv * (h1@W2) )  slice-major [2][n][32]    [gemm2, MFMA]
//   out = dinv*(A.ps2)+b2  fp32   row-major [n][64]         [agg2 x2 slices]
// ---------------------------------------------------------------------------

typedef float f32x4 __attribute__((ext_vector_type(4)));
typedef short bf16x8 __attribute__((ext_vector_type(8)));

#define EPB 4096   // edges per block in bucket pass 1

__device__ inline float bf2f(unsigned short u) {
    return __uint_as_float(((unsigned int)u) << 16);
}
__device__ inline unsigned short f2bf(float f) {
    unsigned int x = __float_as_uint(f);
    x = x + 0x7FFFu + ((x >> 16) & 1u);   // round-to-nearest-even
    return (unsigned short)(x >> 16);
}

__global__ __launch_bounds__(256) void k_init(int* __restrict__ bucket_cnt) {
    bucket_cnt[threadIdx.x] = 0;
}

// Pass 1: per-(bucket,block) offsets via atomicAdd into bucket counters.
// Extra blocks (>= nbR) convert/transpose weights to bf16.
__global__ __launch_bounds__(256) void k_rhist(const int* __restrict__ col,
                                               int* __restrict__ bbase,
                                               int* __restrict__ bucket_cnt,
                                               const float* __restrict__ W1,
                                               const float* __restrict__ W2,
                                               unsigned short* __restrict__ Wt1,
                                               unsigned short* __restrict__ Wt2,
                                               int e, int nbR, int nbB) {
    if ((int)blockIdx.x >= nbR) {
        int i = ((int)blockIdx.x - nbR) * 256 + threadIdx.x;
        if (i < 16384) {                       // W1: 128x128
            int k = i >> 7, nc = i & 127;
            Wt1[nc * 128 + k] = f2bf(W1[i]);
        } else if (i < 24576) {                // W2: 128x64
            int i2 = i - 16384;
            int k = i2 >> 6, nc = i2 & 63;
            Wt2[nc * 128 + k] = f2bf(W2[i2]);
        }
        return;
    }
    __shared__ int h[256];
    int t = threadIdx.x;
    h[t] = 0;
    __syncthreads();
    int base = blockIdx.x * EPB;
#pragma unroll
    for (int i = 0; i < EPB / 256; ++i) {
        int idx = base + t + i * 256;
        if (idx < e) atomicAdd(&h[col[idx] >> 8], 1);
    }
    __syncthreads();
    if (t < nbB) bbase[t * nbR + blockIdx.x] = atomicAdd(&bucket_cnt[t], h[t]);
}

// Tiny single-block exclusive scan of the bucket counts.
__global__ __launch_bounds__(256) void k_scanB(const int* __restrict__ bucket_cnt,
                                               int* __restrict__ bucket_base, int nbB) {
    __shared__ int s[256];
    int t = threadIdx.x;
    int v = (t < nbB) ? bucket_cnt[t] : 0;
    s[t] = v;
    __syncthreads();
#pragma unroll
    for (int off = 1; off < 256; off <<= 1) {
        int u = (t >= off) ? s[t - off] : 0;
        __syncthreads();
        s[t] += u;
        __syncthreads();
    }
    if (t < nbB) bucket_base[t] = s[t] - v;
    if (t == 255) bucket_base[nbB] = s[255];
}

// Pass 1 scatter into bucket-grouped tmp (block-owned runs).
// tmp entry: (col & 255) << 16 | row.
__global__ __launch_bounds__(256) void k_rscatter(const int* __restrict__ row,
                                                  const int* __restrict__ col,
                                                  const int* __restrict__ bucket_base,
                                                  const int* __restrict__ bbase,
                                                  unsigned int* __restrict__ tmp,
                                                  int e, int nbR, int nbB) {
    __shared__ int base[256];
    __shared__ int h[256];
    int t = threadIdx.x;
    base[t] = (t < nbB) ? bucket_base[t] + bbase[t * nbR + blockIdx.x] : 0;
    h[t] = 0;
    __syncthreads();
    int b0 = blockIdx.x * EPB;
#pragma unroll
    for (int i = 0; i < EPB / 256; ++i) {
        int idx = b0 + t + i * 256;
        if (idx < e) {
            int c = col[idx];
            int bin = c >> 8;
            int rk = atomicAdd(&h[bin], 1);
            tmp[base[bin] + rk] =
                ((unsigned int)(c & 255) << 16) | (unsigned int)row[idx];
        }
    }
}

// Per-node degree -> dinv (block per bucket; LDS histogram over tmp range).
__global__ __launch_bounds__(256) void k_deg(const unsigned int* __restrict__ tmp,
                                             const int* __restrict__ bucket_base,
                                             float* __restrict__ dinv, int n) {
    __shared__ int cnt[256];
    int b = blockIdx.x, t = threadIdx.x;
    cnt[t] = 0;
    __syncthreads();
    int beg = bucket_base[b], end = bucket_base[b + 1];
    for (int i = beg + t; i < end; i += 256) atomicAdd(&cnt[tmp[i] >> 16], 1);
    __syncthreads();
    int node = b * 256 + t;
    if (node < n) dinv[node] = rsqrtf((float)cnt[t] + 1.0f);
}

// GEMM1 (MFMA): hs = bf16( dinv[i]*(X@W1) ), slice-major [4][n][32].
__global__ __launch_bounds__(256, 2) void k_gemm1(const float* __restrict__ x,
                                                  const unsigned short* __restrict__ Wt,
                                                  const float* __restrict__ dinv,
                                                  unsigned short* __restrict__ hs, int n) {
    __shared__ unsigned short Xs[128 * 136];
    __shared__ unsigned short Ws[128 * 136];
    __shared__ float dinv_s[128];
    int t = threadIdx.x;
    int r0blk = blockIdx.x * 128;

#pragma unroll
    for (int i = 0; i < 8; ++i) {
        int c = t + i * 256;
        int nc = c >> 4;
        int k0 = (c & 15) * 8;
        bf16x8 v = *(const bf16x8*)&Wt[nc * 128 + k0];
        *(bf16x8*)&Ws[nc * 136 + k0] = v;
    }
#pragma unroll
    for (int i = 0; i < 16; ++i) {
        int c = t + i * 256;
        int r = c >> 5;
        int kq = c & 31;
        float4 v = make_float4(0.f, 0.f, 0.f, 0.f);
        int gr = r0blk + r;
        if (gr < n) v = ((const float4*)x)[gr * 32 + kq];
        ushort4 o;
        o.x = f2bf(v.x); o.y = f2bf(v.y); o.z = f2bf(v.z); o.w = f2bf(v.w);
        *(ushort4*)&Xs[r * 136 + kq * 4] = o;
    }
    if (t < 128) {
        int gr = r0blk + t;
        dinv_s[t] = (gr < n) ? dinv[gr] : 0.f;
    }
    __syncthreads();

    int lane = t & 63, wave = t >> 6;
    int lrow = lane & 15;
    int lk = (lane >> 4) * 8;

    f32x4 acc[2][8];
#pragma unroll
    for (int mi = 0; mi < 2; ++mi)
#pragma unroll
        for (int ni = 0; ni < 8; ++ni) acc[mi][ni] = (f32x4){0.f, 0.f, 0.f, 0.f};

#pragma unroll
    for (int ks = 0; ks < 4; ++ks) {
        int kk = ks * 32 + lk;
        bf16x8 a0 = *(bf16x8*)&Xs[(wave * 32 + lrow) * 136 + kk];
        bf16x8 a1 = *(bf16x8*)&Xs[(wave * 32 + 16 + lrow) * 136 + kk];
#pragma unroll
        for (int ni = 0; ni < 8; ++ni) {
            bf16x8 b = *(bf16x8*)&Ws[(ni * 16 + lrow) * 136 + kk];
            acc[0][ni] = __builtin_amdgcn_mfma_f32_16x16x32_bf16(a0, b, acc[0][ni], 0, 0, 0);
            acc[1][ni] = __builtin_amdgcn_mfma_f32_16x16x32_bf16(a1, b, acc[1][ni], 0, 0, 0);
        }
    }

    int rq = (lane >> 4) * 4;
    size_t ns32 = (size_t)n * 32;
#pragma unroll
    for (int mi = 0; mi < 2; ++mi)
#pragma unroll
        for (int r = 0; r < 4; ++r) {
            int lrw = wave * 32 + mi * 16 + rq + r;
            int grow = r0blk + lrw;
            if (grow < n) {
                float dv = dinv_s[lrw];
#pragma unroll
                for (int ni = 0; ni < 8; ++ni)
                    hs[(size_t)(ni >> 1) * ns32 + (size_t)grow * 32 + (ni & 1) * 16 + lrow] =
                        f2bf(acc[mi][ni][r] * dv);
            }
        }
}

// Agg1: block = (slice s, bucket b). LDS fp32 accumulate of 32 ch over the
// bucket's edges straight from tmp; epilogue adds self-loop + dinv/bias/relu.
// 8 lanes per edge (uint2 = 4 ch each), 8 edges/wave/step, 4-step unroll.
__global__ __launch_bounds__(256) void k_agg1(const unsigned int* __restrict__ tmp,
                                              const int* __restrict__ bucket_base,
                                              const unsigned short* __restrict__ hs,
                                              const float* __restrict__ dinv,
                                              const float* __restrict__ b1,
                                              unsigned short* __restrict__ h1,
                                              int n, int nbB) {
    __shared__ float acc[256][33];
    int s = blockIdx.x / nbB;        // slice-major: temporal slice locality
    int b = blockIdx.x % nbB;
    int t = threadIdx.x;
    for (int i = t; i < 256 * 33; i += 256) ((float*)acc)[i] = 0.f;
    __syncthreads();

    const uint2* hv = (const uint2*)(hs + (size_t)s * n * 32);   // 8 uint2/row
    int beg = bucket_base[b], end = bucket_base[b + 1];
    int lane = t & 63, wid = t >> 6;
    int e8 = lane >> 3, cp = lane & 7;

    int i = beg + wid * 8 + e8;
    for (; i + 96 < end; i += 128) {
        unsigned int u0 = tmp[i];
        unsigned int u1 = tmp[i + 32];
        unsigned int u2 = tmp[i + 64];
        unsigned int u3 = tmp[i + 96];
        uint2 d0 = hv[(u0 & 0xFFFFu) * 8 + cp];
        uint2 d1 = hv[(u1 & 0xFFFFu) * 8 + cp];
        uint2 d2 = hv[(u2 & 0xFFFFu) * 8 + cp];
        uint2 d3 = hv[(u3 & 0xFFFFu) * 8 + cp];
        int c0 = u0 >> 16, c1 = u1 >> 16, c2 = u2 >> 16, c3 = u3 >> 16;
        int q = cp * 4;
        atomicAdd(&acc[c0][q],     bf2f((unsigned short)d0.x));
        atomicAdd(&acc[c0][q + 1], bf2f((unsigned short)(d0.x >> 16)));
        atomicAdd(&acc[c0][q + 2], bf2f((unsigned short)d0.y));
        atomicAdd(&acc[c0][q + 3], bf2f((unsigned short)(d0.y >> 16)));
        atomicAdd(&acc[c1][q],     bf2f((unsigned short)d1.x));
        atomicAdd(&acc[c1][q + 1], bf2f((unsigned short)(d1.x >> 16)));
        atomicAdd(&acc[c1][q + 2], bf2f((unsigned short)d1.y));
        atomicAdd(&acc[c1][q + 3], bf2f((unsigned short)(d1.y >> 16)));
        atomicAdd(&acc[c2][q],     bf2f((unsigned short)d2.x));
        atomicAdd(&acc[c2][q + 1], bf2f((unsigned short)(d2.x >> 16)));
        atomicAdd(&acc[c2][q + 2], bf2f((unsigned short)d2.y));
        atomicAdd(&acc[c2][q + 3], bf2f((unsigned short)(d2.y >> 16)));
        atomicAdd(&acc[c3][q],     bf2f((unsigned short)d3.x));
        atomicAdd(&acc[c3][q + 1], bf2f((unsigned short)(d3.x >> 16)));
        atomicAdd(&acc[c3][q + 2], bf2f((unsigned short)d3.y));
        atomicAdd(&acc[c3][q + 3], bf2f((unsigned short)(d3.y >> 16)));
    }
    for (; i < end; i += 32) {
        unsigned int u = tmp[i];
        uint2 d = hv[(u & 0xFFFFu) * 8 + cp];
        int cl = u >> 16;
        int q = cp * 4;
        atomicAdd(&acc[cl][q],     bf2f((unsigned short)d.x));
        atomicAdd(&acc[cl][q + 1], bf2f((unsigned short)(d.x >> 16)));
        atomicAdd(&acc[cl][q + 2], bf2f((unsigned short)d.y));
        atomicAdd(&acc[cl][q + 3], bf2f((unsigned short)(d.y >> 16)));
    }
    __syncthreads();

    // Epilogue: 256 nodes x 32 ch -> bf16 slice row (uint2 = 4 ch per store).
    uint2* h1v = (uint2*)(h1 + (size_t)s * n * 32);
    for (int idx = t; idx < 2048; idx += 256) {
        int cl = idx >> 3, q2 = idx & 7;
        int node = b * 256 + cl;
        if (node >= n) break;
        uint2 us = hv[node * 8 + q2];             // self-loop row
        float v0 = acc[cl][q2 * 4]     + bf2f((unsigned short)us.x);
        float v1 = acc[cl][q2 * 4 + 1] + bf2f((unsigned short)(us.x >> 16));
        float v2 = acc[cl][q2 * 4 + 2] + bf2f((unsigned short)us.y);
        float v3 = acc[cl][q2 * 4 + 3] + bf2f((unsigned short)(us.y >> 16));
        float dd = dinv[node];
        const float* bb = &b1[s * 32 + q2 * 4];
        v0 = fmaxf(v0 * dd + bb[0], 0.f);
        v1 = fmaxf(v1 * dd + bb[1], 0.f);
        v2 = fmaxf(v2 * dd + bb[2], 0.f);
        v3 = fmaxf(v3 * dd + bb[3], 0.f);
        uint2 o;
        o.x = ((unsigned int)f2bf(v1) << 16) | f2bf(v0);
        o.y = ((unsigned int)f2bf(v3) << 16) | f2bf(v2);
        h1v[(size_t)node * 8 + q2] = o;
    }
}

// GEMM2 (MFMA): ps2 = bf16( dinv[i]*(h1@W2) ). h1 slice-major [4][n][32];
// ps2 slice-major [2][n][32].
__global__ __launch_bounds__(256, 3) void k_gemm2(const unsigned short* __restrict__ h1,
                                                  const unsigned short* __restrict__ Wt,
                                                  const float* __restrict__ dinv,
                                                  unsigned short* __restrict__ ps2, int n) {
    __shared__ unsigned short Xs[128 * 136];
    __shared__ unsigned short Ws[64 * 136];
    __shared__ float dinv_s[128];
    int t = threadIdx.x;
    int r0blk = blockIdx.x * 128;
    size_t ns32 = (size_t)n * 32;

#pragma unroll
    for (int i = 0; i < 4; ++i) {
        int c = t + i * 256;
        int nc = c >> 4;
        int k0 = (c & 15) * 8;
        bf16x8 v = *(const bf16x8*)&Wt[nc * 128 + k0];
        *(bf16x8*)&Ws[nc * 136 + k0] = v;
    }
#pragma unroll
    for (int i = 0; i < 8; ++i) {
        int c = t + i * 256;
        int r = c >> 4;
        int k0 = (c & 15) * 8;
        int gr = r0blk + r;
        bf16x8 v = (bf16x8)(short)0;
        if (gr < n) v = *(const bf16x8*)&h1[(size_t)(k0 >> 5) * ns32 + (size_t)gr * 32 + (k0 & 31)];
        *(bf16x8*)&Xs[r * 136 + k0] = v;
    }
    if (t < 128) {
        int gr = r0blk + t;
        dinv_s[t] = (gr < n) ? dinv[gr] : 0.f;
    }
    __syncthreads();

    int lane = t & 63, wave = t >> 6;
    int lrow = lane & 15;
    int lk = (lane >> 4) * 8;

    f32x4 acc[2][4];
#pragma unroll
    for (int mi = 0; mi < 2; ++mi)
#pragma unroll
        for (int ni = 0; ni < 4; ++ni) acc[mi][ni] = (f32x4){0.f, 0.f, 0.f, 0.f};

#pragma unroll
    for (int ks = 0; ks < 4; ++ks) {
        int kk = ks * 32 + lk;
        bf16x8 a0 = *(bf16x8*)&Xs[(wave * 32 + lrow) * 136 + kk];
        bf16x8 a1 = *(bf16x8*)&Xs[(wave * 32 + 16 + lrow) * 136 + kk];
#pragma unroll
        for (int ni = 0; ni < 4; ++ni) {
            bf16x8 b = *(bf16x8*)&Ws[(ni * 16 + lrow) * 136 + kk];
            acc[0][ni] = __builtin_amdgcn_mfma_f32_16x16x32_bf16(a0, b, acc[0][ni], 0, 0, 0);
            acc[1][ni] = __builtin_amdgcn_mfma_f32_16x16x32_bf16(a1, b, acc[1][ni], 0, 0, 0);
        }
    }

    int rq = (lane >> 4) * 4;
#pragma unroll
    for (int mi = 0; mi < 2; ++mi)
#pragma unroll
        for (int r = 0; r < 4; ++r) {
            int lrw = wave * 32 + mi * 16 + rq + r;
            int grow = r0blk + lrw;
            if (grow < n) {
                float dv = dinv_s[lrw];
#pragma unroll
                for (int ni = 0; ni < 4; ++ni)
                    ps2[(size_t)(ni >> 1) * ns32 + (size_t)grow * 32 + (ni & 1) * 16 + lrow] =
                        f2bf(acc[mi][ni][r] * dv);
            }
        }
}

// Agg2: same bucket-accumulate; 2 slices; fp32 output row-major [n][64].
__global__ __launch_bounds__(256) void k_agg2(const unsigned int* __restrict__ tmp,
                                              const int* __restrict__ bucket_base,
                                              const unsigned short* __restrict__ ps2,
                                              const float* __restrict__ dinv,
                                              const float* __restrict__ b2,
                                              float* __restrict__ out,
                                              int n, int nbB) {
    __shared__ float acc[256][33];
    int s = blockIdx.x / nbB;
    int b = blockIdx.x % nbB;
    int t = threadIdx.x;
    for (int i = t; i < 256 * 33; i += 256) ((float*)acc)[i] = 0.f;
    __syncthreads();

    const uint2* pv = (const uint2*)(ps2 + (size_t)s * n * 32);
    int beg = bucket_base[b], end = bucket_base[b + 1];
    int lane = t & 63, wid = t >> 6;
    int e8 = lane >> 3, cp = lane & 7;

    int i = beg + wid * 8 + e8;
    for (; i + 96 < end; i += 128) {
        unsigned int u0 = tmp[i];
        unsigned int u1 = tmp[i + 32];
        unsigned int u2 = tmp[i + 64];
        unsigned int u3 = tmp[i + 96];
        uint2 d0 = pv[(u0 & 0xFFFFu) * 8 + cp];
        uint2 d1 = pv[(u1 & 0xFFFFu) * 8 + cp];
        uint2 d2 = pv[(u2 & 0xFFFFu) * 8 + cp];
        uint2 d3 = pv[(u3 & 0xFFFFu) * 8 + cp];
        int c0 = u0 >> 16, c1 = u1 >> 16, c2 = u2 >> 16, c3 = u3 >> 16;
        int q = cp * 4;
        atomicAdd(&acc[c0][q],     bf2f((unsigned short)d0.x));
        atomicAdd(&acc[c0][q + 1], bf2f((unsigned short)(d0.x >> 16)));
        atomicAdd(&acc[c0][q + 2], bf2f((unsigned short)d0.y));
        atomicAdd(&acc[c0][q + 3], bf2f((unsigned short)(d0.y >> 16)));
        atomicAdd(&acc[c1][q],     bf2f((unsigned short)d1.x));
        atomicAdd(&acc[c1][q + 1], bf2f((unsigned short)(d1.x >> 16)));
        atomicAdd(&acc[c1][q + 2], bf2f((unsigned short)d1.y));
        atomicAdd(&acc[c1][q + 3], bf2f((unsigned short)(d1.y >> 16)));
        atomicAdd(&acc[c2][q],     bf2f((unsigned short)d2.x));
        atomicAdd(&acc[c2][q + 1], bf2f((unsigned short)(d2.x >> 16)));
        atomicAdd(&acc[c2][q + 2], bf2f((unsigned short)d2.y));
        atomicAdd(&acc[c2][q + 3], bf2f((unsigned short)(d2.y >> 16)));
        atomicAdd(&acc[c3][q],     bf2f((unsigned short)d3.x));
        atomicAdd(&acc[c3][q + 1], bf2f((unsigned short)(d3.x >> 16)));
        atomicAdd(&acc[c3][q + 2], bf2f((unsigned short)d3.y));
        atomicAdd(&acc[c3][q + 3], bf2f((unsigned short)(d3.y >> 16)));
    }
    for (; i < end; i += 32) {
        unsigned int u = tmp[i];
        uint2 d = pv[(u & 0xFFFFu) * 8 + cp];
        int cl = u >> 16;
        int q = cp * 4;
        atomicAdd(&acc[cl][q],     bf2f((unsigned short)d.x));
        atomicAdd(&acc[cl][q + 1], bf2f((unsigned short)(d.x >> 16)));
        atomicAdd(&acc[cl][q + 2], bf2f((unsigned short)d.y));
        atomicAdd(&acc[cl][q + 3], bf2f((unsigned short)(d.y >> 16)));
    }
    __syncthreads();

    // Epilogue: float4 per thread-iter into out[node*64 + s*32 + q4*4].
    for (int idx = t; idx < 2048; idx += 256) {
        int cl = idx >> 3, q4 = idx & 7;
        int node = b * 256 + cl;
        if (node >= n) break;
        uint2 us = pv[node * 8 + q4];             // self-loop row
        float dd = dinv[node];
        const float* bb = &b2[s * 32 + q4 * 4];
        float4 o;
        o.x = (acc[cl][q4 * 4]     + bf2f((unsigned short)us.x))        * dd + bb[0];
        o.y = (acc[cl][q4 * 4 + 1] + bf2f((unsigned short)(us.x >> 16))) * dd + bb[1];
        o.z = (acc[cl][q4 * 4 + 2] + bf2f((unsigned short)us.y))        * dd + bb[2];
        o.w = (acc[cl][q4 * 4 + 3] + bf2f((unsigned short)(us.y >> 16))) * dd + bb[3];
        *(float4*)&out[(size_t)node * 64 + s * 32 + q4 * 4] = o;
    }
}

extern "C" void kernel_launch(void* const* d_in, const int* in_sizes, int n_in,
                              void* d_out, int out_size, void* d_ws, size_t ws_size,
                              hipStream_t stream) {
    const float* x  = (const float*)d_in[0];
    const int*   ei = (const int*)d_in[1];
    const float* W1 = (const float*)d_in[2];
    const float* b1 = (const float*)d_in[3];
    const float* W2 = (const float*)d_in[4];
    const float* b2 = (const float*)d_in[5];
    float* out = (float*)d_out;

    int n = in_sizes[0] / 128;       // 50000
    int e = in_sizes[1] / 2;         // 800000
    const int* row = ei;             // sources
    const int* col = ei + e;         // destinations

    int nbR = (e + EPB - 1) / EPB;   // 196 pass-1 blocks
    int nbB = (n + 255) / 256;       // 196 buckets
    int m   = nbB * nbR;             // 38416 per-(bucket,block) offsets

    // Workspace layout (int units; 16B-aligned sections).
    int* iw = (int*)d_ws;
    size_t o = 0;
    int* bucket_cnt  = iw + o; o += 256;
    int* bucket_base = iw + o; o += 256;                 // nbB+1 <= 197
    int* bbase       = iw + o; o += (size_t)m;           o = (o + 3) & ~(size_t)3;
    float* dinv      = (float*)(iw + o); o += (size_t)n; o = (o + 3) & ~(size_t)3;
    unsigned int* tmp = (unsigned int*)(iw + o); o += (size_t)e; o = (o + 3) & ~(size_t)3;
    unsigned short* Wt1 = (unsigned short*)(iw + o); o += 8192;
    unsigned short* Wt2 = (unsigned short*)(iw + o); o += 4096;
    unsigned short* hs  = (unsigned short*)(iw + o);     // [4][n][32] bf16
    unsigned short* h1  = hs + (size_t)n * 128;          // [4][n][32] bf16
    unsigned short* ps2 = hs;                            // reuse: [2][n][32]

    k_init<<<1, 256, 0, stream>>>(bucket_cnt);
    k_rhist<<<nbR + 96, 256, 0, stream>>>(col, bbase, bucket_cnt, W1, W2, Wt1, Wt2, e, nbR, nbB);
    k_scanB<<<1, 256, 0, stream>>>(bucket_cnt, bucket_base, nbB);
    k_rscatter<<<nbR, 256, 0, stream>>>(row, col, bucket_base, bbase, tmp, e, nbR, nbB);
    k_deg<<<nbB, 256, 0, stream>>>(tmp, bucket_base, dinv, n);

    int nbg = (n + 127) / 128;
    k_gemm1<<<nbg, 256, 0, stream>>>(x, Wt1, dinv, hs, n);
    k_agg1<<<4 * nbB, 256, 0, stream>>>(tmp, bucket_base, hs, dinv, b1, h1, n, nbB);
    k_gemm2<<<nbg, 256, 0, stream>>>(h1, Wt2, dinv, ps2, n);
    k_agg2<<<2 * nbB, 256, 0, stream>>>(tmp, bucket_base, ps2, dinv, b2, out, n, nbB);
}

// Round 8
// 136.520 us; speedup vs baseline: 7.8952x; 7.8952x over previous
//
#include <hip/hip_runtime.h>

// ---------------------------------------------------------------------------
// GCN 2-layer: out = A_norm * relu(A_norm*(X@W1)+b1) @ W2 + b2
// A_norm = D^-1/2 (A + I) D^-1/2.
//
// Round-8: recovery to the measured-best structure (r5, 136us) with r6's
// leaner CSR chain. Row-major bf16 intermediates, MFMA GEMMs, per-node
// wave gathers. (r7's LDS-atomic aggregation: 678us, reverted. r6's sliced
// gathers: 84us vs 35us row-major, reverted.)
//   CSR: memset + rhist(+weight prep) + scanB + rscatter + bsort
//   hs  = bf16( dinv * (X@W1) )   [n][128]   [gemm1, MFMA]
//   h1  = relu(dinv*(A.hs)+b1)    [n][128]   [gather1]
//   ps2 = bf16( dinv * (h1@W2) )  [n][64]    [gemm2, MFMA]
//   out = dinv*(A.ps2)+b2  fp32   [n][64]    [gather2]
// ---------------------------------------------------------------------------

typedef float f32x4 __attribute__((ext_vector_type(4)));
typedef short bf16x8 __attribute__((ext_vector_type(8)));

#define EPB 4096   // edges per block in bucket pass 1

__device__ inline float bf2f(unsigned short u) {
    return __uint_as_float(((unsigned int)u) << 16);
}
__device__ inline unsigned short f2bf(float f) {
    unsigned int x = __float_as_uint(f);
    x = x + 0x7FFFu + ((x >> 16) & 1u);   // round-to-nearest-even
    return (unsigned short)(x >> 16);
}
__device__ inline float4 cvt4(ushort4 u) {
    return make_float4(bf2f(u.x), bf2f(u.y), bf2f(u.z), bf2f(u.w));
}

// Pass 1: per-(bucket,block) offsets via atomicAdd into bucket counters.
// Extra blocks (>= nbR) convert/transpose weights to bf16.
__global__ __launch_bounds__(256) void k_rhist(const int* __restrict__ col,
                                               int* __restrict__ bbase,
                                               int* __restrict__ bucket_cnt,
                                               const float* __restrict__ W1,
                                               const float* __restrict__ W2,
                                               unsigned short* __restrict__ Wt1,
                                               unsigned short* __restrict__ Wt2,
                                               int e, int nbR, int nbB) {
    if ((int)blockIdx.x >= nbR) {
        int i = ((int)blockIdx.x - nbR) * 256 + threadIdx.x;
        if (i < 16384) {                       // W1: 128x128
            int k = i >> 7, nc = i & 127;
            Wt1[nc * 128 + k] = f2bf(W1[i]);
        } else if (i < 24576) {                // W2: 128x64
            int i2 = i - 16384;
            int k = i2 >> 6, nc = i2 & 63;
            Wt2[nc * 128 + k] = f2bf(W2[i2]);
        }
        return;
    }
    __shared__ int h[256];
    int t = threadIdx.x;
    h[t] = 0;
    __syncthreads();
    int base = blockIdx.x * EPB;
#pragma unroll
    for (int i = 0; i < EPB / 256; ++i) {
        int idx = base + t + i * 256;
        if (idx < e) atomicAdd(&h[col[idx] >> 8], 1);
    }
    __syncthreads();
    if (t < nbB) bbase[t * nbR + blockIdx.x] = atomicAdd(&bucket_cnt[t], h[t]);
}

// Tiny single-block exclusive scan of the bucket counts.
__global__ __launch_bounds__(256) void k_scanB(const int* __restrict__ bucket_cnt,
                                               int* __restrict__ bucket_base, int nbB) {
    __shared__ int s[256];
    int t = threadIdx.x;
    int v = (t < nbB) ? bucket_cnt[t] : 0;
    s[t] = v;
    __syncthreads();
#pragma unroll
    for (int off = 1; off < 256; off <<= 1) {
        int u = (t >= off) ? s[t - off] : 0;
        __syncthreads();
        s[t] += u;
        __syncthreads();
    }
    if (t < nbB) bucket_base[t] = s[t] - v;
    if (t == 255) bucket_base[nbB] = s[255];
}

// Pass 1 scatter into bucket-grouped tmp (block-owned runs).
// tmp entry: (col & 255) << 16 | row.
__global__ __launch_bounds__(256) void k_rscatter(const int* __restrict__ row,
                                                  const int* __restrict__ col,
                                                  const int* __restrict__ bucket_base,
                                                  const int* __restrict__ bbase,
                                                  unsigned int* __restrict__ tmp,
                                                  int e, int nbR, int nbB) {
    __shared__ int base[256];
    __shared__ int h[256];
    int t = threadIdx.x;
    base[t] = (t < nbB) ? bucket_base[t] + bbase[t * nbR + blockIdx.x] : 0;
    h[t] = 0;
    __syncthreads();
    int b0 = blockIdx.x * EPB;
#pragma unroll
    for (int i = 0; i < EPB / 256; ++i) {
        int idx = b0 + t + i * 256;
        if (idx < e) {
            int c = col[idx];
            int bin = c >> 8;
            int rk = atomicAdd(&h[bin], 1);
            tmp[base[bin] + rk] =
                ((unsigned int)(c & 255) << 16) | (unsigned int)row[idx];
        }
    }
}

// Pass 2: per-bucket counting sort; emits indptr, dinv, srcidx.
__global__ __launch_bounds__(256) void k_bsort(const unsigned int* __restrict__ tmp,
                                               const int* __restrict__ bucket_base,
                                               int* __restrict__ indptr,
                                               float* __restrict__ dinv,
                                               unsigned short* __restrict__ srcidx,
                                               int n, int e, int nbB) {
    __shared__ int cnt[256];
    __shared__ int pre[256];
    int b = blockIdx.x;
    int t = threadIdx.x;
    int beg = bucket_base[b];
    int end = bucket_base[b + 1];

    cnt[t] = 0;
    __syncthreads();
    for (int i = beg + t; i < end; i += 256) atomicAdd(&cnt[tmp[i] >> 16], 1);
    __syncthreads();
    int v = cnt[t];
    pre[t] = v;
    __syncthreads();
#pragma unroll
    for (int off = 1; off < 256; off <<= 1) {
        int u = (t >= off) ? pre[t - off] : 0;
        __syncthreads();
        pre[t] += u;
        __syncthreads();
    }
    int myexcl = pre[t] - v;
    int node = b * 256 + t;
    if (node < n) {
        indptr[node] = beg + myexcl;
        dinv[node] = rsqrtf((float)v + 1.0f);
    }
    if (b == nbB - 1 && t == 0) indptr[n] = e;
    __syncthreads();
    pre[t] = beg + myexcl;
    cnt[t] = 0;
    __syncthreads();
    for (int i = beg + t; i < end; i += 256) {
        unsigned int u = tmp[i];
        int cl = u >> 16;
        int rk = atomicAdd(&cnt[cl], 1);
        srcidx[pre[cl] + rk] = (unsigned short)(u & 0xFFFFu);
    }
}

// GEMM1 (MFMA): hs = bf16( dinv[i] * (X @ W1) ). Tile 128x128, K=128.
__global__ __launch_bounds__(256, 2) void k_gemm1(const float* __restrict__ x,
                                                  const unsigned short* __restrict__ Wt,
                                                  const float* __restrict__ dinv,
                                                  unsigned short* __restrict__ hs, int n) {
    __shared__ unsigned short Xs[128 * 136];
    __shared__ unsigned short Ws[128 * 136];
    __shared__ float dinv_s[128];
    int t = threadIdx.x;
    int r0blk = blockIdx.x * 128;

#pragma unroll
    for (int i = 0; i < 8; ++i) {
        int c = t + i * 256;
        int nc = c >> 4;
        int k0 = (c & 15) * 8;
        bf16x8 v = *(const bf16x8*)&Wt[nc * 128 + k0];
        *(bf16x8*)&Ws[nc * 136 + k0] = v;
    }
#pragma unroll
    for (int i = 0; i < 16; ++i) {
        int c = t + i * 256;
        int r = c >> 5;
        int kq = c & 31;
        float4 v = make_float4(0.f, 0.f, 0.f, 0.f);
        int gr = r0blk + r;
        if (gr < n) v = ((const float4*)x)[gr * 32 + kq];
        ushort4 o;
        o.x = f2bf(v.x); o.y = f2bf(v.y); o.z = f2bf(v.z); o.w = f2bf(v.w);
        *(ushort4*)&Xs[r * 136 + kq * 4] = o;
    }
    if (t < 128) {
        int gr = r0blk + t;
        dinv_s[t] = (gr < n) ? dinv[gr] : 0.f;
    }
    __syncthreads();

    int lane = t & 63, wave = t >> 6;
    int lrow = lane & 15;
    int lk = (lane >> 4) * 8;

    f32x4 acc[2][8];
#pragma unroll
    for (int mi = 0; mi < 2; ++mi)
#pragma unroll
        for (int ni = 0; ni < 8; ++ni) acc[mi][ni] = (f32x4){0.f, 0.f, 0.f, 0.f};

#pragma unroll
    for (int ks = 0; ks < 4; ++ks) {
        int kk = ks * 32 + lk;
        bf16x8 a0 = *(bf16x8*)&Xs[(wave * 32 + lrow) * 136 + kk];
        bf16x8 a1 = *(bf16x8*)&Xs[(wave * 32 + 16 + lrow) * 136 + kk];
#pragma unroll
        for (int ni = 0; ni < 8; ++ni) {
            bf16x8 b = *(bf16x8*)&Ws[(ni * 16 + lrow) * 136 + kk];
            acc[0][ni] = __builtin_amdgcn_mfma_f32_16x16x32_bf16(a0, b, acc[0][ni], 0, 0, 0);
            acc[1][ni] = __builtin_amdgcn_mfma_f32_16x16x32_bf16(a1, b, acc[1][ni], 0, 0, 0);
        }
    }

    int rq = (lane >> 4) * 4;
#pragma unroll
    for (int mi = 0; mi < 2; ++mi)
#pragma unroll
        for (int r = 0; r < 4; ++r) {
            int lrw = wave * 32 + mi * 16 + rq + r;
            int grow = r0blk + lrw;
            if (grow < n) {
                float dv = dinv_s[lrw];
#pragma unroll
                for (int ni = 0; ni < 8; ++ni)
                    hs[grow * 128 + ni * 16 + lrow] = f2bf(acc[mi][ni][r] * dv);
            }
        }
}

// Gather1: one wave per node, half-wave per edge, ushort4 (4ch)/lane.
__global__ __launch_bounds__(256) void k_gather1(const int* __restrict__ indptr,
                                                 const unsigned short* __restrict__ srcidx,
                                                 const unsigned short* __restrict__ hs,
                                                 const float* __restrict__ dinv,
                                                 const float* __restrict__ b1,
                                                 unsigned short* __restrict__ h1, int n) {
    int wid = (blockIdx.x * 256 + threadIdx.x) >> 6;
    if (wid >= n) return;
    int lane = threadIdx.x & 63;
    int half = lane >> 5;
    int hl = lane & 31;
    const ushort4* hv = (const ushort4*)hs;

    int beg = indptr[wid], end = indptr[wid + 1];
    float4 a0 = make_float4(0.f, 0.f, 0.f, 0.f), a1 = a0, a2 = a0, a3 = a0;

    int j = beg;
    for (; j + 7 < end; j += 8) {
        int sA = srcidx[j + half];
        int sB = srcidx[j + 2 + half];
        int sC = srcidx[j + 4 + half];
        int sD = srcidx[j + 6 + half];
        float4 v;
        v = cvt4(hv[sA * 32 + hl]); a0.x += v.x; a0.y += v.y; a0.z += v.z; a0.w += v.w;
        v = cvt4(hv[sB * 32 + hl]); a1.x += v.x; a1.y += v.y; a1.z += v.z; a1.w += v.w;
        v = cvt4(hv[sC * 32 + hl]); a2.x += v.x; a2.y += v.y; a2.z += v.z; a2.w += v.w;
        v = cvt4(hv[sD * 32 + hl]); a3.x += v.x; a3.y += v.y; a3.z += v.z; a3.w += v.w;
    }
    if (j + half < end) {
        float4 v = cvt4(hv[srcidx[j + half] * 32 + hl]);
        a0.x += v.x; a0.y += v.y; a0.z += v.z; a0.w += v.w;
    }
    j += 2;
    if (j + half < end) {
        float4 v = cvt4(hv[srcidx[j + half] * 32 + hl]);
        a1.x += v.x; a1.y += v.y; a1.z += v.z; a1.w += v.w;
    }
    j += 2;
    if (j + half < end) {
        float4 v = cvt4(hv[srcidx[j + half] * 32 + hl]);
        a2.x += v.x; a2.y += v.y; a2.z += v.z; a2.w += v.w;
    }
    j += 2;
    if (j + half < end) {
        float4 v = cvt4(hv[srcidx[j + half] * 32 + hl]);
        a3.x += v.x; a3.y += v.y; a3.z += v.z; a3.w += v.w;
    }

    float4 sv = cvt4(hv[wid * 32 + hl]);
    if (half == 0) {
        a0.x += sv.x; a0.y += sv.y; a0.z += sv.z; a0.w += sv.w;
    }

    float4 tsum;
    tsum.x = a0.x + a1.x + a2.x + a3.x;
    tsum.y = a0.y + a1.y + a2.y + a3.y;
    tsum.z = a0.z + a1.z + a2.z + a3.z;
    tsum.w = a0.w + a1.w + a2.w + a3.w;
    tsum.x += __shfl_xor(tsum.x, 32);
    tsum.y += __shfl_xor(tsum.y, 32);
    tsum.z += __shfl_xor(tsum.z, 32);
    tsum.w += __shfl_xor(tsum.w, 32);

    if (half == 0) {
        float d = dinv[wid];
        float4 bb = *(const float4*)&b1[hl * 4];
        ushort4 o;
        o.x = f2bf(fmaxf(tsum.x * d + bb.x, 0.f));
        o.y = f2bf(fmaxf(tsum.y * d + bb.y, 0.f));
        o.z = f2bf(fmaxf(tsum.z * d + bb.z, 0.f));
        o.w = f2bf(fmaxf(tsum.w * d + bb.w, 0.f));
        ((ushort4*)h1)[wid * 32 + hl] = o;
    }
}

// GEMM2 (MFMA): ps2 = bf16( dinv[i] * (h1 @ W2) ). Tile 128x64, K=128.
__global__ __launch_bounds__(256, 3) void k_gemm2(const unsigned short* __restrict__ h1,
                                                  const unsigned short* __restrict__ Wt,
                                                  const float* __restrict__ dinv,
                                                  unsigned short* __restrict__ ps2, int n) {
    __shared__ unsigned short Xs[128 * 136];
    __shared__ unsigned short Ws[64 * 136];
    __shared__ float dinv_s[128];
    int t = threadIdx.x;
    int r0blk = blockIdx.x * 128;

#pragma unroll
    for (int i = 0; i < 4; ++i) {
        int c = t + i * 256;
        int nc = c >> 4;
        int k0 = (c & 15) * 8;
        bf16x8 v = *(const bf16x8*)&Wt[nc * 128 + k0];
        *(bf16x8*)&Ws[nc * 136 + k0] = v;
    }
#pragma unroll
    for (int i = 0; i < 8; ++i) {
        int c = t + i * 256;
        int r = c >> 4;
        int k0 = (c & 15) * 8;
        int gr = r0blk + r;
        bf16x8 v = (bf16x8)(short)0;
        if (gr < n) v = *(const bf16x8*)&h1[gr * 128 + k0];
        *(bf16x8*)&Xs[r * 136 + k0] = v;
    }
    if (t < 128) {
        int gr = r0blk + t;
        dinv_s[t] = (gr < n) ? dinv[gr] : 0.f;
    }
    __syncthreads();

    int lane = t & 63, wave = t >> 6;
    int lrow = lane & 15;
    int lk = (lane >> 4) * 8;

    f32x4 acc[2][4];
#pragma unroll
    for (int mi = 0; mi < 2; ++mi)
#pragma unroll
        for (int ni = 0; ni < 4; ++ni) acc[mi][ni] = (f32x4){0.f, 0.f, 0.f, 0.f};

#pragma unroll
    for (int ks = 0; ks < 4; ++ks) {
        int kk = ks * 32 + lk;
        bf16x8 a0 = *(bf16x8*)&Xs[(wave * 32 + lrow) * 136 + kk];
        bf16x8 a1 = *(bf16x8*)&Xs[(wave * 32 + 16 + lrow) * 136 + kk];
#pragma unroll
        for (int ni = 0; ni < 4; ++ni) {
            bf16x8 b = *(bf16x8*)&Ws[(ni * 16 + lrow) * 136 + kk];
            acc[0][ni] = __builtin_amdgcn_mfma_f32_16x16x32_bf16(a0, b, acc[0][ni], 0, 0, 0);
            acc[1][ni] = __builtin_amdgcn_mfma_f32_16x16x32_bf16(a1, b, acc[1][ni], 0, 0, 0);
        }
    }

    int rq = (lane >> 4) * 4;
#pragma unroll
    for (int mi = 0; mi < 2; ++mi)
#pragma unroll
        for (int r = 0; r < 4; ++r) {
            int lrw = wave * 32 + mi * 16 + rq + r;
            int grow = r0blk + lrw;
            if (grow < n) {
                float dv = dinv_s[lrw];
#pragma unroll
                for (int ni = 0; ni < 4; ++ni)
                    ps2[grow * 64 + ni * 16 + lrow] = f2bf(acc[mi][ni][r] * dv);
            }
        }
}

// Gather2: one wave per node, half-wave per edge, uint (2ch)/lane.
__global__ __launch_bounds__(256) void k_gather2(const int* __restrict__ indptr,
                                                 const unsigned short* __restrict__ srcidx,
                                                 const unsigned short* __restrict__ ps2,
                                                 const float* __restrict__ dinv,
                                                 const float* __restrict__ b2,
                                                 float* __restrict__ out, int n) {
    int wid = (blockIdx.x * 256 + threadIdx.x) >> 6;
    if (wid >= n) return;
    int lane = threadIdx.x & 63;
    int half = lane >> 5;
    int hl = lane & 31;
    const unsigned int* pv = (const unsigned int*)ps2;

    int beg = indptr[wid], end = indptr[wid + 1];
    float2 a0 = make_float2(0.f, 0.f), a1 = a0, a2 = a0, a3 = a0;

    int j = beg;
    for (; j + 7 < end; j += 8) {
        int sA = srcidx[j + half];
        int sB = srcidx[j + 2 + half];
        int sC = srcidx[j + 4 + half];
        int sD = srcidx[j + 6 + half];
        unsigned int uA = pv[sA * 32 + hl];
        unsigned int uB = pv[sB * 32 + hl];
        unsigned int uC = pv[sC * 32 + hl];
        unsigned int uD = pv[sD * 32 + hl];
        a0.x += bf2f((unsigned short)uA); a0.y += bf2f((unsigned short)(uA >> 16));
        a1.x += bf2f((unsigned short)uB); a1.y += bf2f((unsigned short)(uB >> 16));
        a2.x += bf2f((unsigned short)uC); a2.y += bf2f((unsigned short)(uC >> 16));
        a3.x += bf2f((unsigned short)uD); a3.y += bf2f((unsigned short)(uD >> 16));
    }
    if (j + half < end) {
        unsigned int u = pv[srcidx[j + half] * 32 + hl];
        a0.x += bf2f((unsigned short)u); a0.y += bf2f((unsigned short)(u >> 16));
    }
    j += 2;
    if (j + half < end) {
        unsigned int u = pv[srcidx[j + half] * 32 + hl];
        a1.x += bf2f((unsigned short)u); a1.y += bf2f((unsigned short)(u >> 16));
    }
    j += 2;
    if (j + half < end) {
        unsigned int u = pv[srcidx[j + half] * 32 + hl];
        a2.x += bf2f((unsigned short)u); a2.y += bf2f((unsigned short)(u >> 16));
    }
    j += 2;
    if (j + half < end) {
        unsigned int u = pv[srcidx[j + half] * 32 + hl];
        a3.x += bf2f((unsigned short)u); a3.y += bf2f((unsigned short)(u >> 16));
    }

    unsigned int us = pv[wid * 32 + hl];
    if (half == 0) {
        a0.x += bf2f((unsigned short)us); a0.y += bf2f((unsigned short)(us >> 16));
    }

    float2 tsum;
    tsum.x = a0.x + a1.x + a2.x + a3.x;
    tsum.y = a0.y + a1.y + a2.y + a3.y;
    tsum.x += __shfl_xor(tsum.x, 32);
    tsum.y += __shfl_xor(tsum.y, 32);

    if (half == 0) {
        float d = dinv[wid];
        float2 bb = *(const float2*)&b2[hl * 2];
        float2 o;
        o.x = tsum.x * d + bb.x;
        o.y = tsum.y * d + bb.y;
        ((float2*)out)[wid * 32 + hl] = o;
    }
}

extern "C" void kernel_launch(void* const* d_in, const int* in_sizes, int n_in,
                              void* d_out, int out_size, void* d_ws, size_t ws_size,
                              hipStream_t stream) {
    const float* x  = (const float*)d_in[0];
    const int*   ei = (const int*)d_in[1];
    const float* W1 = (const float*)d_in[2];
    const float* b1 = (const float*)d_in[3];
    const float* W2 = (const float*)d_in[4];
    const float* b2 = (const float*)d_in[5];
    float* out = (float*)d_out;

    int n = in_sizes[0] / 128;       // 50000
    int e = in_sizes[1] / 2;         // 800000
    const int* row = ei;             // sources
    const int* col = ei + e;         // destinations

    int nbR = (e + EPB - 1) / EPB;   // 196 pass-1 blocks
    int nbB = (n + 255) / 256;       // 196 buckets
    int m   = nbB * nbR;             // 38416 per-(bucket,block) offsets

    // Workspace layout (int units; 16B-aligned sections).
    int* iw = (int*)d_ws;
    size_t o = 0;
    int* bucket_cnt  = iw + o; o += 256;
    int* bucket_base = iw + o; o += 256;                 // nbB+1 <= 197
    int* bbase       = iw + o; o += (size_t)m;           o = (o + 3) & ~(size_t)3;
    int* indptr      = iw + o; o += (size_t)(n + 1);     o = (o + 3) & ~(size_t)3;
    float* dinv      = (float*)(iw + o); o += (size_t)n; o = (o + 3) & ~(size_t)3;
    unsigned int* tmp = (unsigned int*)(iw + o); o += (size_t)e; o = (o + 3) & ~(size_t)3;
    unsigned short* srcidx = (unsigned short*)(iw + o); o += (size_t)(e / 2 + 2); o = (o + 3) & ~(size_t)3;
    unsigned short* Wt1 = (unsigned short*)(iw + o); o += 8192;
    unsigned short* Wt2 = (unsigned short*)(iw + o); o += 4096;
    unsigned short* hs  = (unsigned short*)(iw + o);     // [n][128] bf16
    unsigned short* h1  = hs + (size_t)n * 128;          // [n][128] bf16
    unsigned short* ps2 = hs;                            // reuse: [n][64]

    hipMemsetAsync(bucket_cnt, 0, 256 * sizeof(int), stream);
    k_rhist<<<nbR + 96, 256, 0, stream>>>(col, bbase, bucket_cnt, W1, W2, Wt1, Wt2, e, nbR, nbB);
    k_scanB<<<1, 256, 0, stream>>>(bucket_cnt, bucket_base, nbB);
    k_rscatter<<<nbR, 256, 0, stream>>>(row, col, bucket_base, bbase, tmp, e, nbR, nbB);
    k_bsort<<<nbB, 256, 0, stream>>>(tmp, bucket_base, indptr, dinv, srcidx, n, e, nbB);

    int nbg = (n + 127) / 128;
    k_gemm1<<<nbg, 256, 0, stream>>>(x, Wt1, dinv, hs, n);
    k_gather1<<<(n * 64 + 255) / 256, 256, 0, stream>>>(indptr, srcidx, hs, dinv, b1, h1, n);
    k_gemm2<<<nbg, 256, 0, stream>>>(h1, Wt2, dinv, ps2, n);
    k_gather2<<<(n * 64 + 255) / 256, 256, 0, stream>>>(indptr, srcidx, ps2, dinv, b2, out, n);
}

// Round 9
// 136.439 us; speedup vs baseline: 7.8998x; 1.0006x over previous
//
#include <hip/hip_runtime.h>

// ---------------------------------------------------------------------------
// GCN 2-layer: out = A_norm * relu(A_norm*(X@W1)+b1) @ W2 + b2
// A_norm = D^-1/2 (A + I) D^-1/2.
//
// Round-9: r8 structure (136us) + (a) 8-deep contiguous-half gathers,
// (b) k_scanB folded into rscatter/bsort via local LDS scans.
//   CSR: memset + rhist(+weight prep) + rscatter + bsort
//   hs  = bf16( dinv * (X@W1) )   [n][128]   [gemm1, MFMA]
//   h1  = relu(dinv*(A.hs)+b1)    [n][128]   [gather1]
//   ps2 = bf16( dinv * (h1@W2) )  [n][64]    [gemm2, MFMA]
//   out = dinv*(A.ps2)+b2  fp32   [n][64]    [gather2]
// ---------------------------------------------------------------------------

typedef float f32x4 __attribute__((ext_vector_type(4)));
typedef short bf16x8 __attribute__((ext_vector_type(8)));

#define EPB 4096   // edges per block in bucket pass 1

__device__ inline float bf2f(unsigned short u) {
    return __uint_as_float(((unsigned int)u) << 16);
}
__device__ inline unsigned short f2bf(float f) {
    unsigned int x = __float_as_uint(f);
    x = x + 0x7FFFu + ((x >> 16) & 1u);   // round-to-nearest-even
    return (unsigned short)(x >> 16);
}
__device__ inline float4 cvt4(ushort4 u) {
    return make_float4(bf2f(u.x), bf2f(u.y), bf2f(u.z), bf2f(u.w));
}
__device__ inline void add4(float4& a, float4 v) {
    a.x += v.x; a.y += v.y; a.z += v.z; a.w += v.w;
}

// Pass 1: per-(bucket,block) offsets via atomicAdd into bucket counters.
// Extra blocks (>= nbR) convert/transpose weights to bf16.
__global__ __launch_bounds__(256) void k_rhist(const int* __restrict__ col,
                                               int* __restrict__ bbase,
                                               int* __restrict__ bucket_cnt,
                                               const float* __restrict__ W1,
                                               const float* __restrict__ W2,
                                               unsigned short* __restrict__ Wt1,
                                               unsigned short* __restrict__ Wt2,
                                               int e, int nbR, int nbB) {
    if ((int)blockIdx.x >= nbR) {
        int i = ((int)blockIdx.x - nbR) * 256 + threadIdx.x;
        if (i < 16384) {                       // W1: 128x128
            int k = i >> 7, nc = i & 127;
            Wt1[nc * 128 + k] = f2bf(W1[i]);
        } else if (i < 24576) {                // W2: 128x64
            int i2 = i - 16384;
            int k = i2 >> 6, nc = i2 & 63;
            Wt2[nc * 128 + k] = f2bf(W2[i2]);
        }
        return;
    }
    __shared__ int h[256];
    int t = threadIdx.x;
    h[t] = 0;
    __syncthreads();
    int base = blockIdx.x * EPB;
#pragma unroll
    for (int i = 0; i < EPB / 256; ++i) {
        int idx = base + t + i * 256;
        if (idx < e) atomicAdd(&h[col[idx] >> 8], 1);
    }
    __syncthreads();
    if (t < nbB) bbase[t * nbR + blockIdx.x] = atomicAdd(&bucket_cnt[t], h[t]);
}

// Pass 1 scatter into bucket-grouped tmp (block-owned runs). Bucket bases are
// re-derived locally by a 256-wide LDS scan of bucket_cnt (no k_scanB).
// tmp entry: (col & 255) << 16 | row.
__global__ __launch_bounds__(256) void k_rscatter(const int* __restrict__ row,
                                                  const int* __restrict__ col,
                                                  const int* __restrict__ bucket_cnt,
                                                  const int* __restrict__ bbase,
                                                  unsigned int* __restrict__ tmp,
                                                  int e, int nbR, int nbB) {
    __shared__ int base[256];
    __shared__ int h[256];
    int t = threadIdx.x;
    int v = (t < nbB) ? bucket_cnt[t] : 0;
    base[t] = v;
    __syncthreads();
#pragma unroll
    for (int off = 1; off < 256; off <<= 1) {
        int u = (t >= off) ? base[t - off] : 0;
        __syncthreads();
        base[t] += u;
        __syncthreads();
    }
    int excl = base[t] - v;                    // exclusive bucket base
    base[t] = excl + ((t < nbB) ? bbase[t * nbR + blockIdx.x] : 0);
    h[t] = 0;
    __syncthreads();
    int b0 = blockIdx.x * EPB;
#pragma unroll
    for (int i = 0; i < EPB / 256; ++i) {
        int idx = b0 + t + i * 256;
        if (idx < e) {
            int c = col[idx];
            int bin = c >> 8;
            int rk = atomicAdd(&h[bin], 1);
            tmp[base[bin] + rk] =
                ((unsigned int)(c & 255) << 16) | (unsigned int)row[idx];
        }
    }
}

// Pass 2: per-bucket counting sort; emits indptr, dinv, srcidx. Bucket range
// re-derived locally from bucket_cnt.
__global__ __launch_bounds__(256) void k_bsort(const unsigned int* __restrict__ tmp,
                                               const int* __restrict__ bucket_cnt,
                                               int* __restrict__ indptr,
                                               float* __restrict__ dinv,
                                               unsigned short* __restrict__ srcidx,
                                               int n, int e, int nbB) {
    __shared__ int cnt[256];
    __shared__ int pre[256];
    int b = blockIdx.x;
    int t = threadIdx.x;

    int v = (t < nbB) ? bucket_cnt[t] : 0;
    pre[t] = v;
    __syncthreads();
#pragma unroll
    for (int off = 1; off < 256; off <<= 1) {
        int u = (t >= off) ? pre[t - off] : 0;
        __syncthreads();
        pre[t] += u;
        __syncthreads();
    }
    int beg = pre[b] - ((b < nbB) ? bucket_cnt[b] : 0);   // exclusive at b
    int end = pre[b];                                     // inclusive at b
    __syncthreads();

    cnt[t] = 0;
    __syncthreads();
    for (int i = beg + t; i < end; i += 256) atomicAdd(&cnt[tmp[i] >> 16], 1);
    __syncthreads();
    v = cnt[t];
    pre[t] = v;
    __syncthreads();
#pragma unroll
    for (int off = 1; off < 256; off <<= 1) {
        int u = (t >= off) ? pre[t - off] : 0;
        __syncthreads();
        pre[t] += u;
        __syncthreads();
    }
    int myexcl = pre[t] - v;
    int node = b * 256 + t;
    if (node < n) {
        indptr[node] = beg + myexcl;
        dinv[node] = rsqrtf((float)v + 1.0f);
    }
    if (b == nbB - 1 && t == 0) indptr[n] = e;
    __syncthreads();
    pre[t] = beg + myexcl;
    cnt[t] = 0;
    __syncthreads();
    for (int i = beg + t; i < end; i += 256) {
        unsigned int u = tmp[i];
        int cl = u >> 16;
        int rk = atomicAdd(&cnt[cl], 1);
        srcidx[pre[cl] + rk] = (unsigned short)(u & 0xFFFFu);
    }
}

// GEMM1 (MFMA): hs = bf16( dinv[i] * (X @ W1) ). Tile 128x128, K=128.
__global__ __launch_bounds__(256, 2) void k_gemm1(const float* __restrict__ x,
                                                  const unsigned short* __restrict__ Wt,
                                                  const float* __restrict__ dinv,
                                                  unsigned short* __restrict__ hs, int n) {
    __shared__ unsigned short Xs[128 * 136];
    __shared__ unsigned short Ws[128 * 136];
    __shared__ float dinv_s[128];
    int t = threadIdx.x;
    int r0blk = blockIdx.x * 128;

#pragma unroll
    for (int i = 0; i < 8; ++i) {
        int c = t + i * 256;
        int nc = c >> 4;
        int k0 = (c & 15) * 8;
        bf16x8 v = *(const bf16x8*)&Wt[nc * 128 + k0];
        *(bf16x8*)&Ws[nc * 136 + k0] = v;
    }
#pragma unroll
    for (int i = 0; i < 16; ++i) {
        int c = t + i * 256;
        int r = c >> 5;
        int kq = c & 31;
        float4 v = make_float4(0.f, 0.f, 0.f, 0.f);
        int gr = r0blk + r;
        if (gr < n) v = ((const float4*)x)[gr * 32 + kq];
        ushort4 o;
        o.x = f2bf(v.x); o.y = f2bf(v.y); o.z = f2bf(v.z); o.w = f2bf(v.w);
        *(ushort4*)&Xs[r * 136 + kq * 4] = o;
    }
    if (t < 128) {
        int gr = r0blk + t;
        dinv_s[t] = (gr < n) ? dinv[gr] : 0.f;
    }
    __syncthreads();

    int lane = t & 63, wave = t >> 6;
    int lrow = lane & 15;
    int lk = (lane >> 4) * 8;

    f32x4 acc[2][8];
#pragma unroll
    for (int mi = 0; mi < 2; ++mi)
#pragma unroll
        for (int ni = 0; ni < 8; ++ni) acc[mi][ni] = (f32x4){0.f, 0.f, 0.f, 0.f};

#pragma unroll
    for (int ks = 0; ks < 4; ++ks) {
        int kk = ks * 32 + lk;
        bf16x8 a0 = *(bf16x8*)&Xs[(wave * 32 + lrow) * 136 + kk];
        bf16x8 a1 = *(bf16x8*)&Xs[(wave * 32 + 16 + lrow) * 136 + kk];
#pragma unroll
        for (int ni = 0; ni < 8; ++ni) {
            bf16x8 b = *(bf16x8*)&Ws[(ni * 16 + lrow) * 136 + kk];
            acc[0][ni] = __builtin_amdgcn_mfma_f32_16x16x32_bf16(a0, b, acc[0][ni], 0, 0, 0);
            acc[1][ni] = __builtin_amdgcn_mfma_f32_16x16x32_bf16(a1, b, acc[1][ni], 0, 0, 0);
        }
    }

    int rq = (lane >> 4) * 4;
#pragma unroll
    for (int mi = 0; mi < 2; ++mi)
#pragma unroll
        for (int r = 0; r < 4; ++r) {
            int lrw = wave * 32 + mi * 16 + rq + r;
            int grow = r0blk + lrw;
            if (grow < n) {
                float dv = dinv_s[lrw];
#pragma unroll
                for (int ni = 0; ni < 8; ++ni)
                    hs[grow * 128 + ni * 16 + lrow] = f2bf(acc[mi][ni][r] * dv);
            }
        }
}

// Gather1: one wave per node; each half-wave takes a CONTIGUOUS half of the
// edge list, 8 gathers in flight per lane; halves combined via shfl_xor(32).
__global__ __launch_bounds__(256) void k_gather1(const int* __restrict__ indptr,
                                                 const unsigned short* __restrict__ srcidx,
                                                 const unsigned short* __restrict__ hs,
                                                 const float* __restrict__ dinv,
                                                 const float* __restrict__ b1,
                                                 unsigned short* __restrict__ h1, int n) {
    int wid = (blockIdx.x * 256 + threadIdx.x) >> 6;
    if (wid >= n) return;
    int lane = threadIdx.x & 63;
    int half = lane >> 5;
    int hl = lane & 31;
    const ushort4* hv = (const ushort4*)hs;   // row stride 32 ushort4

    int beg = indptr[wid], end = indptr[wid + 1];
    int c0 = (end - beg + 1) >> 1;
    int j    = beg + half * c0;
    int jend = half ? end : (beg + c0);

    float4 a0 = make_float4(0.f, 0.f, 0.f, 0.f), a1 = a0, a2 = a0, a3 = a0;

    for (; j + 7 < jend; j += 8) {
        int s0 = srcidx[j],     s1 = srcidx[j + 1];
        int s2 = srcidx[j + 2], s3 = srcidx[j + 3];
        int s4 = srcidx[j + 4], s5 = srcidx[j + 5];
        int s6 = srcidx[j + 6], s7 = srcidx[j + 7];
        float4 v0 = cvt4(hv[s0 * 32 + hl]);
        float4 v1 = cvt4(hv[s1 * 32 + hl]);
        float4 v2 = cvt4(hv[s2 * 32 + hl]);
        float4 v3 = cvt4(hv[s3 * 32 + hl]);
        float4 v4 = cvt4(hv[s4 * 32 + hl]);
        float4 v5 = cvt4(hv[s5 * 32 + hl]);
        float4 v6 = cvt4(hv[s6 * 32 + hl]);
        float4 v7 = cvt4(hv[s7 * 32 + hl]);
        add4(a0, v0); add4(a1, v1); add4(a2, v2); add4(a3, v3);
        add4(a0, v4); add4(a1, v5); add4(a2, v6); add4(a3, v7);
    }
    if (j + 3 < jend) {
        int s0 = srcidx[j], s1 = srcidx[j + 1], s2 = srcidx[j + 2], s3 = srcidx[j + 3];
        add4(a0, cvt4(hv[s0 * 32 + hl]));
        add4(a1, cvt4(hv[s1 * 32 + hl]));
        add4(a2, cvt4(hv[s2 * 32 + hl]));
        add4(a3, cvt4(hv[s3 * 32 + hl]));
        j += 4;
    }
    for (; j < jend; ++j) add4(a0, cvt4(hv[srcidx[j] * 32 + hl]));

    if (half == 0) add4(a1, cvt4(hv[wid * 32 + hl]));   // self-loop once

    float4 tsum;
    tsum.x = a0.x + a1.x + a2.x + a3.x;
    tsum.y = a0.y + a1.y + a2.y + a3.y;
    tsum.z = a0.z + a1.z + a2.z + a3.z;
    tsum.w = a0.w + a1.w + a2.w + a3.w;
    tsum.x += __shfl_xor(tsum.x, 32);
    tsum.y += __shfl_xor(tsum.y, 32);
    tsum.z += __shfl_xor(tsum.z, 32);
    tsum.w += __shfl_xor(tsum.w, 32);

    if (half == 0) {
        float d = dinv[wid];
        float4 bb = *(const float4*)&b1[hl * 4];
        ushort4 o;
        o.x = f2bf(fmaxf(tsum.x * d + bb.x, 0.f));
        o.y = f2bf(fmaxf(tsum.y * d + bb.y, 0.f));
        o.z = f2bf(fmaxf(tsum.z * d + bb.z, 0.f));
        o.w = f2bf(fmaxf(tsum.w * d + bb.w, 0.f));
        ((ushort4*)h1)[wid * 32 + hl] = o;
    }
}

// GEMM2 (MFMA): ps2 = bf16( dinv[i] * (h1 @ W2) ). Tile 128x64, K=128.
__global__ __launch_bounds__(256, 3) void k_gemm2(const unsigned short* __restrict__ h1,
                                                  const unsigned short* __restrict__ Wt,
                                                  const float* __restrict__ dinv,
                                                  unsigned short* __restrict__ ps2, int n) {
    __shared__ unsigned short Xs[128 * 136];
    __shared__ unsigned short Ws[64 * 136];
    __shared__ float dinv_s[128];
    int t = threadIdx.x;
    int r0blk = blockIdx.x * 128;

#pragma unroll
    for (int i = 0; i < 4; ++i) {
        int c = t + i * 256;
        int nc = c >> 4;
        int k0 = (c & 15) * 8;
        bf16x8 v = *(const bf16x8*)&Wt[nc * 128 + k0];
        *(bf16x8*)&Ws[nc * 136 + k0] = v;
    }
#pragma unroll
    for (int i = 0; i < 8; ++i) {
        int c = t + i * 256;
        int r = c >> 4;
        int k0 = (c & 15) * 8;
        int gr = r0blk + r;
        bf16x8 v = (bf16x8)(short)0;
        if (gr < n) v = *(const bf16x8*)&h1[gr * 128 + k0];
        *(bf16x8*)&Xs[r * 136 + k0] = v;
    }
    if (t < 128) {
        int gr = r0blk + t;
        dinv_s[t] = (gr < n) ? dinv[gr] : 0.f;
    }
    __syncthreads();

    int lane = t & 63, wave = t >> 6;
    int lrow = lane & 15;
    int lk = (lane >> 4) * 8;

    f32x4 acc[2][4];
#pragma unroll
    for (int mi = 0; mi < 2; ++mi)
#pragma unroll
        for (int ni = 0; ni < 4; ++ni) acc[mi][ni] = (f32x4){0.f, 0.f, 0.f, 0.f};

#pragma unroll
    for (int ks = 0; ks < 4; ++ks) {
        int kk = ks * 32 + lk;
        bf16x8 a0 = *(bf16x8*)&Xs[(wave * 32 + lrow) * 136 + kk];
        bf16x8 a1 = *(bf16x8*)&Xs[(wave * 32 + 16 + lrow) * 136 + kk];
#pragma unroll
        for (int ni = 0; ni < 4; ++ni) {
            bf16x8 b = *(bf16x8*)&Ws[(ni * 16 + lrow) * 136 + kk];
            acc[0][ni] = __builtin_amdgcn_mfma_f32_16x16x32_bf16(a0, b, acc[0][ni], 0, 0, 0);
            acc[1][ni] = __builtin_amdgcn_mfma_f32_16x16x32_bf16(a1, b, acc[1][ni], 0, 0, 0);
        }
    }

    int rq = (lane >> 4) * 4;
#pragma unroll
    for (int mi = 0; mi < 2; ++mi)
#pragma unroll
        for (int r = 0; r < 4; ++r) {
            int lrw = wave * 32 + mi * 16 + rq + r;
            int grow = r0blk + lrw;
            if (grow < n) {
                float dv = dinv_s[lrw];
#pragma unroll
                for (int ni = 0; ni < 4; ++ni)
                    ps2[grow * 64 + ni * 16 + lrow] = f2bf(acc[mi][ni][r] * dv);
            }
        }
}

// Gather2: one wave per node; contiguous half-runs, 8 in flight, uint/lane.
__global__ __launch_bounds__(256) void k_gather2(const int* __restrict__ indptr,
                                                 const unsigned short* __restrict__ srcidx,
                                                 const unsigned short* __restrict__ ps2,
                                                 const float* __restrict__ dinv,
                                                 const float* __restrict__ b2,
                                                 float* __restrict__ out, int n) {
    int wid = (blockIdx.x * 256 + threadIdx.x) >> 6;
    if (wid >= n) return;
    int lane = threadIdx.x & 63;
    int half = lane >> 5;
    int hl = lane & 31;
    const unsigned int* pv = (const unsigned int*)ps2;   // row stride 32 uints

    int beg = indptr[wid], end = indptr[wid + 1];
    int c0 = (end - beg + 1) >> 1;
    int j    = beg + half * c0;
    int jend = half ? end : (beg + c0);

    float2 a0 = make_float2(0.f, 0.f), a1 = a0, a2 = a0, a3 = a0;

    for (; j + 7 < jend; j += 8) {
        int s0 = srcidx[j],     s1 = srcidx[j + 1];
        int s2 = srcidx[j + 2], s3 = srcidx[j + 3];
        int s4 = srcidx[j + 4], s5 = srcidx[j + 5];
        int s6 = srcidx[j + 6], s7 = srcidx[j + 7];
        unsigned int u0 = pv[s0 * 32 + hl];
        unsigned int u1 = pv[s1 * 32 + hl];
        unsigned int u2 = pv[s2 * 32 + hl];
        unsigned int u3 = pv[s3 * 32 + hl];
        unsigned int u4 = pv[s4 * 32 + hl];
        unsigned int u5 = pv[s5 * 32 + hl];
        unsigned int u6 = pv[s6 * 32 + hl];
        unsigned int u7 = pv[s7 * 32 + hl];
        a0.x += bf2f((unsigned short)u0); a0.y += bf2f((unsigned short)(u0 >> 16));
        a1.x += bf2f((unsigned short)u1); a1.y += bf2f((unsigned short)(u1 >> 16));
        a2.x += bf2f((unsigned short)u2); a2.y += bf2f((unsigned short)(u2 >> 16));
        a3.x += bf2f((unsigned short)u3); a3.y += bf2f((unsigned short)(u3 >> 16));
        a0.x += bf2f((unsigned short)u4); a0.y += bf2f((unsigned short)(u4 >> 16));
        a1.x += bf2f((unsigned short)u5); a1.y += bf2f((unsigned short)(u5 >> 16));
        a2.x += bf2f((unsigned short)u6); a2.y += bf2f((unsigned short)(u6 >> 16));
        a3.x += bf2f((unsigned short)u7); a3.y += bf2f((unsigned short)(u7 >> 16));
    }
    if (j + 3 < jend) {
        int s0 = srcidx[j], s1 = srcidx[j + 1], s2 = srcidx[j + 2], s3 = srcidx[j + 3];
        unsigned int u0 = pv[s0 * 32 + hl];
        unsigned int u1 = pv[s1 * 32 + hl];
        unsigned int u2 = pv[s2 * 32 + hl];
        unsigned int u3 = pv[s3 * 32 + hl];
        a0.x += bf2f((unsigned short)u0); a0.y += bf2f((unsigned short)(u0 >> 16));
        a1.x += bf2f((unsigned short)u1); a1.y += bf2f((unsigned short)(u1 >> 16));
        a2.x += bf2f((unsigned short)u2); a2.y += bf2f((unsigned short)(u2 >> 16));
        a3.x += bf2f((unsigned short)u3); a3.y += bf2f((unsigned short)(u3 >> 16));
        j += 4;
    }
    for (; j < jend; ++j) {
        unsigned int u = pv[srcidx[j] * 32 + hl];
        a0.x += bf2f((unsigned short)u); a0.y += bf2f((unsigned short)(u >> 16));
    }

    if (half == 0) {   // self-loop once
        unsigned int u = pv[wid * 32 + hl];
        a1.x += bf2f((unsigned short)u); a1.y += bf2f((unsigned short)(u >> 16));
    }

    float2 tsum;
    tsum.x = a0.x + a1.x + a2.x + a3.x;
    tsum.y = a0.y + a1.y + a2.y + a3.y;
    tsum.x += __shfl_xor(tsum.x, 32);
    tsum.y += __shfl_xor(tsum.y, 32);

    if (half == 0) {
        float d = dinv[wid];
        float2 bb = *(const float2*)&b2[hl * 2];
        float2 o;
        o.x = tsum.x * d + bb.x;
        o.y = tsum.y * d + bb.y;
        ((float2*)out)[wid * 32 + hl] = o;
    }
}

extern "C" void kernel_launch(void* const* d_in, const int* in_sizes, int n_in,
                              void* d_out, int out_size, void* d_ws, size_t ws_size,
                              hipStream_t stream) {
    const float* x  = (const float*)d_in[0];
    const int*   ei = (const int*)d_in[1];
    const float* W1 = (const float*)d_in[2];
    const float* b1 = (const float*)d_in[3];
    const float* W2 = (const float*)d_in[4];
    const float* b2 = (const float*)d_in[5];
    float* out = (float*)d_out;

    int n = in_sizes[0] / 128;       // 50000
    int e = in_sizes[1] / 2;         // 800000
    const int* row = ei;             // sources
    const int* col = ei + e;         // destinations

    int nbR = (e + EPB - 1) / EPB;   // 196 pass-1 blocks
    int nbB = (n + 255) / 256;       // 196 buckets
    int m   = nbB * nbR;             // 38416 per-(bucket,block) offsets

    // Workspace layout (int units; 16B-aligned sections).
    int* iw = (int*)d_ws;
    size_t o = 0;
    int* bucket_cnt  = iw + o; o += 256;
    int* bbase       = iw + o; o += (size_t)m;           o = (o + 3) & ~(size_t)3;
    int* indptr      = iw + o; o += (size_t)(n + 1);     o = (o + 3) & ~(size_t)3;
    float* dinv      = (float*)(iw + o); o += (size_t)n; o = (o + 3) & ~(size_t)3;
    unsigned int* tmp = (unsigned int*)(iw + o); o += (size_t)e; o = (o + 3) & ~(size_t)3;
    unsigned short* srcidx = (unsigned short*)(iw + o); o += (size_t)(e / 2 + 2); o = (o + 3) & ~(size_t)3;
    unsigned short* Wt1 = (unsigned short*)(iw + o); o += 8192;
    unsigned short* Wt2 = (unsigned short*)(iw + o); o += 4096;
    unsigned short* hs  = (unsigned short*)(iw + o);     // [n][128] bf16
    unsigned short* h1  = hs + (size_t)n * 128;          // [n][128] bf16
    unsigned short* ps2 = hs;                            // reuse: [n][64]

    hipMemsetAsync(bucket_cnt, 0, 256 * sizeof(int), stream);
    k_rhist<<<nbR + 96, 256, 0, stream>>>(col, bbase, bucket_cnt, W1, W2, Wt1, Wt2, e, nbR, nbB);
    k_rscatter<<<nbR, 256, 0, stream>>>(row, col, bucket_cnt, bbase, tmp, e, nbR, nbB);
    k_bsort<<<nbB, 256, 0, stream>>>(tmp, bucket_cnt, indptr, dinv, srcidx, n, e, nbB);

    int nbg = (n + 127) / 128;
    k_gemm1<<<nbg, 256, 0, stream>>>(x, Wt1, dinv, hs, n);
    k_gather1<<<(n * 64 + 255) / 256, 256, 0, stream>>>(indptr, srcidx, hs, dinv, b1, h1, n);
    k_gemm2<<<nbg, 256, 0, stream>>>(h1, Wt2, dinv, ps2, n);
    k_gather2<<<(n * 64 + 255) / 256, 256, 0, stream>>>(indptr, srcidx, ps2, dinv, b2, out, n);
}

// Round 10
// 131.036 us; speedup vs baseline: 8.2255x; 1.0412x over previous
//
#include <hip/hip_runtime.h>

// ---------------------------------------------------------------------------
// GCN 2-layer: out = A_norm * relu(A_norm*(X@W1)+b1) @ W2 + b2
// A_norm = D^-1/2 (A + I) D^-1/2.
//
// Round-10: r9 structure with rscatter+gemm1 FUSED into one dispatch
// (block-index split). Enabled by deferring the dinv[row] pre-scale of hs
// into gather1 (per-edge broadcast dinv[src] load) so gemm1 has no
// dependency on the CSR chain's dinv output.
//   CSR: memset + rhist(+weight prep) + {rscatter || gemm1} + bsort
//   hs  = bf16( X@W1 )  UNSCALED      [n][128]   [fused gemm1, MFMA]
//   h1  = relu(dinv[c]*(sum dinv[s]*hs[s] + dinv[c]*hs[c]) + b1)  [gather1]
//   ps2 = bf16( dinv * (h1@W2) )      [n][64]    [gemm2, MFMA]
//   out = dinv*(A.ps2)+b2  fp32       [n][64]    [gather2]
// ---------------------------------------------------------------------------

typedef float f32x4 __attribute__((ext_vector_type(4)));
typedef short bf16x8 __attribute__((ext_vector_type(8)));

#define EPB 4096   // edges per block in bucket pass 1

__device__ inline float bf2f(unsigned short u) {
    return __uint_as_float(((unsigned int)u) << 16);
}
__device__ inline unsigned short f2bf(float f) {
    unsigned int x = __float_as_uint(f);
    x = x + 0x7FFFu + ((x >> 16) & 1u);   // round-to-nearest-even
    return (unsigned short)(x >> 16);
}
__device__ inline float4 cvt4(ushort4 u) {
    return make_float4(bf2f(u.x), bf2f(u.y), bf2f(u.z), bf2f(u.w));
}
__device__ inline void fma4(float4& a, float4 v, float d) {
    a.x += v.x * d; a.y += v.y * d; a.z += v.z * d; a.w += v.w * d;
}

// Pass 1: per-(bucket,block) offsets via atomicAdd into bucket counters.
// Extra blocks (>= nbR) convert/transpose weights to bf16.
__global__ __launch_bounds__(256) void k_rhist(const int* __restrict__ col,
                                               int* __restrict__ bbase,
                                               int* __restrict__ bucket_cnt,
                                               const float* __restrict__ W1,
                                               const float* __restrict__ W2,
                                               unsigned short* __restrict__ Wt1,
                                               unsigned short* __restrict__ Wt2,
                                               int e, int nbR, int nbB) {
    if ((int)blockIdx.x >= nbR) {
        int i = ((int)blockIdx.x - nbR) * 256 + threadIdx.x;
        if (i < 16384) {                       // W1: 128x128
            int k = i >> 7, nc = i & 127;
            Wt1[nc * 128 + k] = f2bf(W1[i]);
        } else if (i < 24576) {                // W2: 128x64
            int i2 = i - 16384;
            int k = i2 >> 6, nc = i2 & 63;
            Wt2[nc * 128 + k] = f2bf(W2[i2]);
        }
        return;
    }
    __shared__ int h[256];
    int t = threadIdx.x;
    h[t] = 0;
    __syncthreads();
    int base = blockIdx.x * EPB;
#pragma unroll
    for (int i = 0; i < EPB / 256; ++i) {
        int idx = base + t + i * 256;
        if (idx < e) atomicAdd(&h[col[idx] >> 8], 1);
    }
    __syncthreads();
    if (t < nbB) bbase[t * nbR + blockIdx.x] = atomicAdd(&bucket_cnt[t], h[t]);
}

// FUSED dispatch: blocks [0,nbR) = bucket scatter; blocks [nbR,nbR+nbg) =
// gemm1 (hs = bf16(X@W1), unscaled). The two halves are independent.
__global__ __launch_bounds__(256, 2) void k_fused(const int* __restrict__ row,
                                                  const int* __restrict__ col,
                                                  const int* __restrict__ bucket_cnt,
                                                  const int* __restrict__ bbase,
                                                  unsigned int* __restrict__ tmp,
                                                  const float* __restrict__ x,
                                                  const unsigned short* __restrict__ Wt,
                                                  unsigned short* __restrict__ hs,
                                                  int e, int n, int nbR, int nbB) {
    __shared__ int sbase[256];
    __shared__ int sh[256];
    __shared__ unsigned short Xs[128 * 136];
    __shared__ unsigned short Ws[128 * 136];
    int t = threadIdx.x;

    if ((int)blockIdx.x < nbR) {
        // ---- bucket scatter (tmp entry: (col&255)<<16 | row) ----
        int v = (t < nbB) ? bucket_cnt[t] : 0;
        sbase[t] = v;
        __syncthreads();
#pragma unroll
        for (int off = 1; off < 256; off <<= 1) {
            int u = (t >= off) ? sbase[t - off] : 0;
            __syncthreads();
            sbase[t] += u;
            __syncthreads();
        }
        int excl = sbase[t] - v;
        sbase[t] = excl + ((t < nbB) ? bbase[t * nbR + blockIdx.x] : 0);
        sh[t] = 0;
        __syncthreads();
        int b0 = blockIdx.x * EPB;
#pragma unroll
        for (int i = 0; i < EPB / 256; ++i) {
            int idx = b0 + t + i * 256;
            if (idx < e) {
                int c = col[idx];
                int bin = c >> 8;
                int rk = atomicAdd(&sh[bin], 1);
                tmp[sbase[bin] + rk] =
                    ((unsigned int)(c & 255) << 16) | (unsigned int)row[idx];
            }
        }
        return;
    }

    // ---- gemm1: tile 128x128, K=128, MFMA 16x16x32 ----
    int r0blk = ((int)blockIdx.x - nbR) * 128;

#pragma unroll
    for (int i = 0; i < 8; ++i) {
        int c = t + i * 256;
        int nc = c >> 4;
        int k0 = (c & 15) * 8;
        bf16x8 v = *(const bf16x8*)&Wt[nc * 128 + k0];
        *(bf16x8*)&Ws[nc * 136 + k0] = v;
    }
#pragma unroll
    for (int i = 0; i < 16; ++i) {
        int c = t + i * 256;
        int r = c >> 5;
        int kq = c & 31;
        float4 v = make_float4(0.f, 0.f, 0.f, 0.f);
        int gr = r0blk + r;
        if (gr < n) v = ((const float4*)x)[gr * 32 + kq];
        ushort4 o;
        o.x = f2bf(v.x); o.y = f2bf(v.y); o.z = f2bf(v.z); o.w = f2bf(v.w);
        *(ushort4*)&Xs[r * 136 + kq * 4] = o;
    }
    __syncthreads();

    int lane = t & 63, wave = t >> 6;
    int lrow = lane & 15;
    int lk = (lane >> 4) * 8;

    f32x4 acc[2][8];
#pragma unroll
    for (int mi = 0; mi < 2; ++mi)
#pragma unroll
        for (int ni = 0; ni < 8; ++ni) acc[mi][ni] = (f32x4){0.f, 0.f, 0.f, 0.f};

#pragma unroll
    for (int ks = 0; ks < 4; ++ks) {
        int kk = ks * 32 + lk;
        bf16x8 a0 = *(bf16x8*)&Xs[(wave * 32 + lrow) * 136 + kk];
        bf16x8 a1 = *(bf16x8*)&Xs[(wave * 32 + 16 + lrow) * 136 + kk];
#pragma unroll
        for (int ni = 0; ni < 8; ++ni) {
            bf16x8 b = *(bf16x8*)&Ws[(ni * 16 + lrow) * 136 + kk];
            acc[0][ni] = __builtin_amdgcn_mfma_f32_16x16x32_bf16(a0, b, acc[0][ni], 0, 0, 0);
            acc[1][ni] = __builtin_amdgcn_mfma_f32_16x16x32_bf16(a1, b, acc[1][ni], 0, 0, 0);
        }
    }

    int rq = (lane >> 4) * 4;
#pragma unroll
    for (int mi = 0; mi < 2; ++mi)
#pragma unroll
        for (int r = 0; r < 4; ++r) {
            int lrw = wave * 32 + mi * 16 + rq + r;
            int grow = r0blk + lrw;
            if (grow < n) {
#pragma unroll
                for (int ni = 0; ni < 8; ++ni)
                    hs[grow * 128 + ni * 16 + lrow] = f2bf(acc[mi][ni][r]);
            }
        }
}

// Pass 2: per-bucket counting sort; emits indptr, dinv, srcidx. Bucket range
// re-derived locally from bucket_cnt.
__global__ __launch_bounds__(256) void k_bsort(const unsigned int* __restrict__ tmp,
                                               const int* __restrict__ bucket_cnt,
                                               int* __restrict__ indptr,
                                               float* __restrict__ dinv,
                                               unsigned short* __restrict__ srcidx,
                                               int n, int e, int nbB) {
    __shared__ int cnt[256];
    __shared__ int pre[256];
    int b = blockIdx.x;
    int t = threadIdx.x;

    int v = (t < nbB) ? bucket_cnt[t] : 0;
    pre[t] = v;
    __syncthreads();
#pragma unroll
    for (int off = 1; off < 256; off <<= 1) {
        int u = (t >= off) ? pre[t - off] : 0;
        __syncthreads();
        pre[t] += u;
        __syncthreads();
    }
    int beg = pre[b] - ((b < nbB) ? bucket_cnt[b] : 0);
    int end = pre[b];
    __syncthreads();

    cnt[t] = 0;
    __syncthreads();
    for (int i = beg + t; i < end; i += 256) atomicAdd(&cnt[tmp[i] >> 16], 1);
    __syncthreads();
    v = cnt[t];
    pre[t] = v;
    __syncthreads();
#pragma unroll
    for (int off = 1; off < 256; off <<= 1) {
        int u = (t >= off) ? pre[t - off] : 0;
        __syncthreads();
        pre[t] += u;
        __syncthreads();
    }
    int myexcl = pre[t] - v;
    int node = b * 256 + t;
    if (node < n) {
        indptr[node] = beg + myexcl;
        dinv[node] = rsqrtf((float)v + 1.0f);
    }
    if (b == nbB - 1 && t == 0) indptr[n] = e;
    __syncthreads();
    pre[t] = beg + myexcl;
    cnt[t] = 0;
    __syncthreads();
    for (int i = beg + t; i < end; i += 256) {
        unsigned int u = tmp[i];
        int cl = u >> 16;
        int rk = atomicAdd(&cnt[cl], 1);
        srcidx[pre[cl] + rk] = (unsigned short)(u & 0xFFFFu);
    }
}

// Gather1: one wave per node; contiguous half-runs, 8 gathers in flight.
// Deferred norm: accumulate dinv[src]*hs_raw[src]; epilogue *dinv[col].
__global__ __launch_bounds__(256) void k_gather1(const int* __restrict__ indptr,
                                                 const unsigned short* __restrict__ srcidx,
                                                 const unsigned short* __restrict__ hs,
                                                 const float* __restrict__ dinv,
                                                 const float* __restrict__ b1,
                                                 unsigned short* __restrict__ h1, int n) {
    int wid = (blockIdx.x * 256 + threadIdx.x) >> 6;
    if (wid >= n) return;
    int lane = threadIdx.x & 63;
    int half = lane >> 5;
    int hl = lane & 31;
    const ushort4* hv = (const ushort4*)hs;   // row stride 32 ushort4

    int beg = indptr[wid], end = indptr[wid + 1];
    int c0 = (end - beg + 1) >> 1;
    int j    = beg + half * c0;
    int jend = half ? end : (beg + c0);

    float4 a0 = make_float4(0.f, 0.f, 0.f, 0.f), a1 = a0, a2 = a0, a3 = a0;

    for (; j + 7 < jend; j += 8) {
        int s0 = srcidx[j],     s1 = srcidx[j + 1];
        int s2 = srcidx[j + 2], s3 = srcidx[j + 3];
        int s4 = srcidx[j + 4], s5 = srcidx[j + 5];
        int s6 = srcidx[j + 6], s7 = srcidx[j + 7];
        float d0 = dinv[s0], d1 = dinv[s1], d2 = dinv[s2], d3 = dinv[s3];
        float d4 = dinv[s4], d5 = dinv[s5], d6 = dinv[s6], d7 = dinv[s7];
        float4 v0 = cvt4(hv[s0 * 32 + hl]);
        float4 v1 = cvt4(hv[s1 * 32 + hl]);
        float4 v2 = cvt4(hv[s2 * 32 + hl]);
        float4 v3 = cvt4(hv[s3 * 32 + hl]);
        float4 v4 = cvt4(hv[s4 * 32 + hl]);
        float4 v5 = cvt4(hv[s5 * 32 + hl]);
        float4 v6 = cvt4(hv[s6 * 32 + hl]);
        float4 v7 = cvt4(hv[s7 * 32 + hl]);
        fma4(a0, v0, d0); fma4(a1, v1, d1); fma4(a2, v2, d2); fma4(a3, v3, d3);
        fma4(a0, v4, d4); fma4(a1, v5, d5); fma4(a2, v6, d6); fma4(a3, v7, d7);
    }
    if (j + 3 < jend) {
        int s0 = srcidx[j], s1 = srcidx[j + 1], s2 = srcidx[j + 2], s3 = srcidx[j + 3];
        fma4(a0, cvt4(hv[s0 * 32 + hl]), dinv[s0]);
        fma4(a1, cvt4(hv[s1 * 32 + hl]), dinv[s1]);
        fma4(a2, cvt4(hv[s2 * 32 + hl]), dinv[s2]);
        fma4(a3, cvt4(hv[s3 * 32 + hl]), dinv[s3]);
        j += 4;
    }
    for (; j < jend; ++j) {
        int s0 = srcidx[j];
        fma4(a0, cvt4(hv[s0 * 32 + hl]), dinv[s0]);
    }

    float dw = dinv[wid];
    if (half == 0) fma4(a1, cvt4(hv[wid * 32 + hl]), dw);   // self-loop once

    float4 tsum;
    tsum.x = a0.x + a1.x + a2.x + a3.x;
    tsum.y = a0.y + a1.y + a2.y + a3.y;
    tsum.z = a0.z + a1.z + a2.z + a3.z;
    tsum.w = a0.w + a1.w + a2.w + a3.w;
    tsum.x += __shfl_xor(tsum.x, 32);
    tsum.y += __shfl_xor(tsum.y, 32);
    tsum.z += __shfl_xor(tsum.z, 32);
    tsum.w += __shfl_xor(tsum.w, 32);

    if (half == 0) {
        float4 bb = *(const float4*)&b1[hl * 4];
        ushort4 o;
        o.x = f2bf(fmaxf(tsum.x * dw + bb.x, 0.f));
        o.y = f2bf(fmaxf(tsum.y * dw + bb.y, 0.f));
        o.z = f2bf(fmaxf(tsum.z * dw + bb.z, 0.f));
        o.w = f2bf(fmaxf(tsum.w * dw + bb.w, 0.f));
        ((ushort4*)h1)[wid * 32 + hl] = o;
    }
}

// GEMM2 (MFMA): ps2 = bf16( dinv[i] * (h1 @ W2) ). Tile 128x64, K=128.
__global__ __launch_bounds__(256, 3) void k_gemm2(const unsigned short* __restrict__ h1,
                                                  const unsigned short* __restrict__ Wt,
                                                  const float* __restrict__ dinv,
                                                  unsigned short* __restrict__ ps2, int n) {
    __shared__ unsigned short Xs[128 * 136];
    __shared__ unsigned short Ws[64 * 136];
    __shared__ float dinv_s[128];
    int t = threadIdx.x;
    int r0blk = blockIdx.x * 128;

#pragma unroll
    for (int i = 0; i < 4; ++i) {
        int c = t + i * 256;
        int nc = c >> 4;
        int k0 = (c & 15) * 8;
        bf16x8 v = *(const bf16x8*)&Wt[nc * 128 + k0];
        *(bf16x8*)&Ws[nc * 136 + k0] = v;
    }
#pragma unroll
    for (int i = 0; i < 8; ++i) {
        int c = t + i * 256;
        int r = c >> 4;
        int k0 = (c & 15) * 8;
        int gr = r0blk + r;
        bf16x8 v = (bf16x8)(short)0;
        if (gr < n) v = *(const bf16x8*)&h1[gr * 128 + k0];
        *(bf16x8*)&Xs[r * 136 + k0] = v;
    }
    if (t < 128) {
        int gr = r0blk + t;
        dinv_s[t] = (gr < n) ? dinv[gr] : 0.f;
    }
    __syncthreads();

    int lane = t & 63, wave = t >> 6;
    int lrow = lane & 15;
    int lk = (lane >> 4) * 8;

    f32x4 acc[2][4];
#pragma unroll
    for (int mi = 0; mi < 2; ++mi)
#pragma unroll
        for (int ni = 0; ni < 4; ++ni) acc[mi][ni] = (f32x4){0.f, 0.f, 0.f, 0.f};

#pragma unroll
    for (int ks = 0; ks < 4; ++ks) {
        int kk = ks * 32 + lk;
        bf16x8 a0 = *(bf16x8*)&Xs[(wave * 32 + lrow) * 136 + kk];
        bf16x8 a1 = *(bf16x8*)&Xs[(wave * 32 + 16 + lrow) * 136 + kk];
#pragma unroll
        for (int ni = 0; ni < 4; ++ni) {
            bf16x8 b = *(bf16x8*)&Ws[(ni * 16 + lrow) * 136 + kk];
            acc[0][ni] = __builtin_amdgcn_mfma_f32_16x16x32_bf16(a0, b, acc[0][ni], 0, 0, 0);
            acc[1][ni] = __builtin_amdgcn_mfma_f32_16x16x32_bf16(a1, b, acc[1][ni], 0, 0, 0);
        }
    }

    int rq = (lane >> 4) * 4;
#pragma unroll
    for (int mi = 0; mi < 2; ++mi)
#pragma unroll
        for (int r = 0; r < 4; ++r) {
            int lrw = wave * 32 + mi * 16 + rq + r;
            int grow = r0blk + lrw;
            if (grow < n) {
                float dv = dinv_s[lrw];
#pragma unroll
                for (int ni = 0; ni < 4; ++ni)
                    ps2[grow * 64 + ni * 16 + lrow] = f2bf(acc[mi][ni][r] * dv);
            }
        }
}

// Gather2: one wave per node; contiguous half-runs, 8 in flight, uint/lane.
__global__ __launch_bounds__(256) void k_gather2(const int* __restrict__ indptr,
                                                 const unsigned short* __restrict__ srcidx,
                                                 const unsigned short* __restrict__ ps2,
                                                 const float* __restrict__ dinv,
                                                 const float* __restrict__ b2,
                                                 float* __restrict__ out, int n) {
    int wid = (blockIdx.x * 256 + threadIdx.x) >> 6;
    if (wid >= n) return;
    int lane = threadIdx.x & 63;
    int half = lane >> 5;
    int hl = lane & 31;
    const unsigned int* pv = (const unsigned int*)ps2;   // row stride 32 uints

    int beg = indptr[wid], end = indptr[wid + 1];
    int c0 = (end - beg + 1) >> 1;
    int j    = beg + half * c0;
    int jend = half ? end : (beg + c0);

    float2 a0 = make_float2(0.f, 0.f), a1 = a0, a2 = a0, a3 = a0;

    for (; j + 7 < jend; j += 8) {
        int s0 = srcidx[j],     s1 = srcidx[j + 1];
        int s2 = srcidx[j + 2], s3 = srcidx[j + 3];
        int s4 = srcidx[j + 4], s5 = srcidx[j + 5];
        int s6 = srcidx[j + 6], s7 = srcidx[j + 7];
        unsigned int u0 = pv[s0 * 32 + hl];
        unsigned int u1 = pv[s1 * 32 + hl];
        unsigned int u2 = pv[s2 * 32 + hl];
        unsigned int u3 = pv[s3 * 32 + hl];
        unsigned int u4 = pv[s4 * 32 + hl];
        unsigned int u5 = pv[s5 * 32 + hl];
        unsigned int u6 = pv[s6 * 32 + hl];
        unsigned int u7 = pv[s7 * 32 + hl];
        a0.x += bf2f((unsigned short)u0); a0.y += bf2f((unsigned short)(u0 >> 16));
        a1.x += bf2f((unsigned short)u1); a1.y += bf2f((unsigned short)(u1 >> 16));
        a2.x += bf2f((unsigned short)u2); a2.y += bf2f((unsigned short)(u2 >> 16));
        a3.x += bf2f((unsigned short)u3); a3.y += bf2f((unsigned short)(u3 >> 16));
        a0.x += bf2f((unsigned short)u4); a0.y += bf2f((unsigned short)(u4 >> 16));
        a1.x += bf2f((unsigned short)u5); a1.y += bf2f((unsigned short)(u5 >> 16));
        a2.x += bf2f((unsigned short)u6); a2.y += bf2f((unsigned short)(u6 >> 16));
        a3.x += bf2f((unsigned short)u7); a3.y += bf2f((unsigned short)(u7 >> 16));
    }
    if (j + 3 < jend) {
        int s0 = srcidx[j], s1 = srcidx[j + 1], s2 = srcidx[j + 2], s3 = srcidx[j + 3];
        unsigned int u0 = pv[s0 * 32 + hl];
        unsigned int u1 = pv[s1 * 32 + hl];
        unsigned int u2 = pv[s2 * 32 + hl];
        unsigned int u3 = pv[s3 * 32 + hl];
        a0.x += bf2f((unsigned short)u0); a0.y += bf2f((unsigned short)(u0 >> 16));
        a1.x += bf2f((unsigned short)u1); a1.y += bf2f((unsigned short)(u1 >> 16));
        a2.x += bf2f((unsigned short)u2); a2.y += bf2f((unsigned short)(u2 >> 16));
        a3.x += bf2f((unsigned short)u3); a3.y += bf2f((unsigned short)(u3 >> 16));
        j += 4;
    }
    for (; j < jend; ++j) {
        unsigned int u = pv[srcidx[j] * 32 + hl];
        a0.x += bf2f((unsigned short)u); a0.y += bf2f((unsigned short)(u >> 16));
    }

    if (half == 0) {   // self-loop once
        unsigned int u = pv[wid * 32 + hl];
        a1.x += bf2f((unsigned short)u); a1.y += bf2f((unsigned short)(u >> 16));
    }

    float2 tsum;
    tsum.x = a0.x + a1.x + a2.x + a3.x;
    tsum.y = a0.y + a1.y + a2.y + a3.y;
    tsum.x += __shfl_xor(tsum.x, 32);
    tsum.y += __shfl_xor(tsum.y, 32);

    if (half == 0) {
        float d = dinv[wid];
        float2 bb = *(const float2*)&b2[hl * 2];
        float2 o;
        o.x = tsum.x * d + bb.x;
        o.y = tsum.y * d + bb.y;
        ((float2*)out)[wid * 32 + hl] = o;
    }
}

extern "C" void kernel_launch(void* const* d_in, const int* in_sizes, int n_in,
                              void* d_out, int out_size, void* d_ws, size_t ws_size,
                              hipStream_t stream) {
    const float* x  = (const float*)d_in[0];
    const int*   ei = (const int*)d_in[1];
    const float* W1 = (const float*)d_in[2];
    const float* b1 = (const float*)d_in[3];
    const float* W2 = (const float*)d_in[4];
    const float* b2 = (const float*)d_in[5];
    float* out = (float*)d_out;

    int n = in_sizes[0] / 128;       // 50000
    int e = in_sizes[1] / 2;         // 800000
    const int* row = ei;             // sources
    const int* col = ei + e;         // destinations

    int nbR = (e + EPB - 1) / EPB;   // 196 pass-1 blocks
    int nbB = (n + 255) / 256;       // 196 buckets
    int m   = nbB * nbR;             // 38416 per-(bucket,block) offsets
    int nbg = (n + 127) / 128;       // 391 gemm blocks

    // Workspace layout (int units; 16B-aligned sections).
    int* iw = (int*)d_ws;
    size_t o = 0;
    int* bucket_cnt  = iw + o; o += 256;
    int* bbase       = iw + o; o += (size_t)m;           o = (o + 3) & ~(size_t)3;
    int* indptr      = iw + o; o += (size_t)(n + 1);     o = (o + 3) & ~(size_t)3;
    float* dinv      = (float*)(iw + o); o += (size_t)n; o = (o + 3) & ~(size_t)3;
    unsigned int* tmp = (unsigned int*)(iw + o); o += (size_t)e; o = (o + 3) & ~(size_t)3;
    unsigned short* srcidx = (unsigned short*)(iw + o); o += (size_t)(e / 2 + 2); o = (o + 3) & ~(size_t)3;
    unsigned short* Wt1 = (unsigned short*)(iw + o); o += 8192;
    unsigned short* Wt2 = (unsigned short*)(iw + o); o += 4096;
    unsigned short* hs  = (unsigned short*)(iw + o);     // [n][128] bf16 (unscaled)
    unsigned short* h1  = hs + (size_t)n * 128;          // [n][128] bf16
    unsigned short* ps2 = hs;                            // reuse: [n][64]

    hipMemsetAsync(bucket_cnt, 0, 256 * sizeof(int), stream);
    k_rhist<<<nbR + 96, 256, 0, stream>>>(col, bbase, bucket_cnt, W1, W2, Wt1, Wt2, e, nbR, nbB);
    k_fused<<<nbR + nbg, 256, 0, stream>>>(row, col, bucket_cnt, bbase, tmp, x, Wt1, hs, e, n, nbR, nbB);
    k_bsort<<<nbB, 256, 0, stream>>>(tmp, bucket_cnt, indptr, dinv, srcidx, n, e, nbB);

    k_gather1<<<(n * 64 + 255) / 256, 256, 0, stream>>>(indptr, srcidx, hs, dinv, b1, h1, n);
    k_gemm2<<<nbg, 256, 0, stream>>>(h1, Wt2, dinv, ps2, n);
    k_gather2<<<(n * 64 + 255) / 256, 256, 0, stream>>>(indptr, srcidx, ps2, dinv, b2, out, n);
}